// Round 11
// baseline (5370.821 us; speedup 1.0000x reference)
//
#include <hip/hip_runtime.h>
#include <math.h>

#define HD    512
#define BATCH 256
#define TDIM  240
#define INDIM 300

typedef unsigned short u16;
typedef u16   u16x8 __attribute__((ext_vector_type(8)));
typedef float f32x4 __attribute__((ext_vector_type(4)));

// ---------------------------------------------------------------------------
// bf16 split: v = hi + lo (RTE). 3-term MFMA product -> ~2^-17 rel error.
// ---------------------------------------------------------------------------
__device__ __forceinline__ u16 bf16_rte(float v) {
    unsigned u = __builtin_bit_cast(unsigned, v);
    unsigned r = (u + 0x7FFFu + ((u >> 16) & 1u)) >> 16;
    return (u16)r;
}

__device__ __forceinline__ void mfma16(f32x4& d, u16x8 a, u16x8 b) {
    asm("v_mfma_f32_16x16x32_bf16 %0, %1, %2, %0" : "+v"(d) : "v"(a), "v"(b));
}

__global__ __launch_bounds__(256) void split_pad(
    const float* __restrict__ src, u16* __restrict__ hi, u16* __restrict__ lo,
    int rows, int kin, int kout)
{
    long i = (long)blockIdx.x * 256 + threadIdx.x;
    if (i >= (long)rows * kout) return;
    int r = (int)(i / kout);
    int k = (int)(i - (long)r * kout);
    float v = (k < kin) ? src[(long)r * kin + k] : 0.f;
    u16 h = bf16_rte(v);
    float hf = __builtin_bit_cast(float, (unsigned)h << 16);
    hi[i] = h;
    lo[i] = bf16_rte(v - hf);
}

// ---------------------------------------------------------------------------
// step_mfma: r3-VERIFIED single-wave step kernel (body-t0 dual + fallback).
// ---------------------------------------------------------------------------
struct StepDir {
    const u16* Wih_h; const u16* Wih_l;
    const u16* Whh_h; const u16* Whh_l;
    const float* bih; const float* bhh;
    const u16* hh; const u16* hl;
    u16* oh; u16* ol;
    float* c;
    float* ex; long exs;
    int t;
};

__global__ __launch_bounds__(64) void step_mfma(
    const u16* __restrict__ xh, const u16* __restrict__ xl,
    StepDir d0, StepDir d1)
{
    StepDir D = blockIdx.z ? d1 : d0;
    const int gx   = blockIdx.x;
    const int xcd  = gx & 7, j = gx >> 3;
    const int cblk = xcd * 4 + (j & 3);
    const int rblk = j >> 2;
    const int lane = threadIdx.x;
    const int lr   = lane & 15;
    const int lk8  = (lane >> 4) * 8;
    const int b0   = rblk * 32;
    const int col  = cblk * 16 + lr;

    f32x4 acc[2][4];
    #pragma unroll
    for (int g = 0; g < 4; ++g) {
        float bs = D.bih[g * HD + col] + D.bhh[g * HD + col];
        acc[0][g] = f32x4{bs, bs, bs, bs};
        acc[1][g] = f32x4{bs, bs, bs, bs};
    }

    u16x8 Ah0[2], Al0[2], Bh0[4], Bl0[4];
    u16x8 Ah1[2], Al1[2], Bh1[4], Bl1[4];

    auto MMA = [&](u16x8 (&Ah)[2], u16x8 (&Al)[2], u16x8 (&Bh)[4], u16x8 (&Bl)[4]) {
        #pragma unroll
        for (int rt = 0; rt < 2; ++rt)
            #pragma unroll
            for (int g = 0; g < 4; ++g) {
                mfma16(acc[rt][g], Ah[rt], Bh[g]);
                mfma16(acc[rt][g], Ah[rt], Bl[g]);
                mfma16(acc[rt][g], Al[rt], Bh[g]);
            }
    };

    {
        auto LD = [&](u16x8 (&Ah)[2], u16x8 (&Al)[2], u16x8 (&Bh)[4], u16x8 (&Bl)[4], int ks) {
            const int ko = ks * 32 + lk8;
            #pragma unroll
            for (int rt = 0; rt < 2; ++rt) {
                long off = ((long)(b0 + rt * 16 + lr) * TDIM + D.t) * 320 + ko;
                Ah[rt] = *(const u16x8*)(xh + off);
                Al[rt] = *(const u16x8*)(xl + off);
            }
            #pragma unroll
            for (int g = 0; g < 4; ++g) {
                long off = (long)(g * HD + col) * 320 + ko;
                Bh[g] = *(const u16x8*)(D.Wih_h + off);
                Bl[g] = *(const u16x8*)(D.Wih_l + off);
            }
        };
        LD(Ah0, Al0, Bh0, Bl0, 0);
        #pragma unroll
        for (int ks = 0; ks < 10; ks += 2) {
            LD(Ah1, Al1, Bh1, Bl1, ks + 1);
            MMA(Ah0, Al0, Bh0, Bl0);
            if (ks + 2 < 10) LD(Ah0, Al0, Bh0, Bl0, ks + 2);
            MMA(Ah1, Al1, Bh1, Bl1);
        }
    }
    {
        auto LD = [&](u16x8 (&Ah)[2], u16x8 (&Al)[2], u16x8 (&Bh)[4], u16x8 (&Bl)[4], int ks) {
            const int ko = ks * 32 + lk8;
            #pragma unroll
            for (int rt = 0; rt < 2; ++rt) {
                long off = (long)(b0 + rt * 16 + lr) * HD + ko;
                Ah[rt] = *(const u16x8*)(D.hh + off);
                Al[rt] = *(const u16x8*)(D.hl + off);
            }
            #pragma unroll
            for (int g = 0; g < 4; ++g) {
                long off = (long)(g * HD + col) * HD + ko;
                Bh[g] = *(const u16x8*)(D.Whh_h + off);
                Bl[g] = *(const u16x8*)(D.Whh_l + off);
            }
        };
        LD(Ah0, Al0, Bh0, Bl0, 0);
        #pragma unroll
        for (int ks = 0; ks < 16; ks += 2) {
            LD(Ah1, Al1, Bh1, Bl1, ks + 1);
            MMA(Ah0, Al0, Bh0, Bl0);
            if (ks + 2 < 16) LD(Ah0, Al0, Bh0, Bl0, ks + 2);
            MMA(Ah1, Al1, Bh1, Bl1);
        }
    }

    #pragma unroll
    for (int rt = 0; rt < 2; ++rt) {
        #pragma unroll
        for (int r = 0; r < 4; ++r) {
            const int b = b0 + rt * 16 + (lane >> 4) * 4 + r;
            const long hoff = (long)b * HD + col;
            float iv = acc[rt][0][r];
            float fv = acc[rt][1][r];
            float gv = acc[rt][2][r];
            float ov = acc[rt][3][r];
            float cp = D.c[hoff];
            float si = 1.f / (1.f + expf(-iv));
            float sf = 1.f / (1.f + expf(-fv));
            float so = 1.f / (1.f + expf(-ov));
            float cn = sf * cp + si * tanhf(gv);
            float hn = so * tanhf(cn);
            D.c[hoff] = cn;
            u16 hb = bf16_rte(hn);
            D.oh[hoff] = hb;
            D.ol[hoff] = bf16_rte(hn - __builtin_bit_cast(float, (unsigned)hb << 16));
            if (D.ex) D.ex[(long)b * D.exs + col] = hn;
        }
    }
}

// ---------------------------------------------------------------------------
// xg_job: one 32-row x 32-col xg tile (r6-verified numerics, single source of
// truth shared by the standalone kernel and the in-persist producers):
//   xgT[tloc][col][row] = bias[col] + x[t0abs + tstep*tloc] @ Wih^T
// ---------------------------------------------------------------------------
__device__ __forceinline__ void xg_job(
    int bx, int lane,
    const u16* __restrict__ xh, const u16* __restrict__ xl,
    const u16* __restrict__ Wih_h, const u16* __restrict__ Wih_l,
    const float* __restrict__ bih, const float* __restrict__ bhh,
    float* __restrict__ xgT, int t0abs, int tstep)
{
    const int tloc = bx >> 9;
    const int rem  = bx & 511;
    const int rblk = rem >> 6;
    const int cgrp = rem & 63;
    const int lr = lane & 15, lk8 = (lane >> 4) * 8;
    const int b0 = rblk * 32;
    const int tx = t0abs + tstep * tloc;
    const int colf0 = cgrp * 32 + lr;
    const int colf1 = colf0 + 16;

    f32x4 acc[2][2];
    {
        float bs0 = bih[colf0] + bhh[colf0];
        float bs1 = bih[colf1] + bhh[colf1];
        acc[0][0] = f32x4{bs0, bs0, bs0, bs0};
        acc[1][0] = f32x4{bs0, bs0, bs0, bs0};
        acc[0][1] = f32x4{bs1, bs1, bs1, bs1};
        acc[1][1] = f32x4{bs1, bs1, bs1, bs1};
    }

    u16x8 a0h[2], a0l[2], b0h[2], b0l[2];
    u16x8 a1h[2], a1l[2], b1h[2], b1l[2];

    auto LD = [&](u16x8 (&Ah)[2], u16x8 (&Al)[2], u16x8 (&Bh)[2], u16x8 (&Bl)[2], int ks) {
        const int ko = ks * 32 + lk8;
        #pragma unroll
        for (int rt = 0; rt < 2; ++rt) {
            long off = ((long)(b0 + rt * 16 + lr) * TDIM + tx) * 320 + ko;
            Ah[rt] = *(const u16x8*)(xh + off);
            Al[rt] = *(const u16x8*)(xl + off);
        }
        long w0 = (long)colf0 * 320 + ko;
        long w1 = (long)colf1 * 320 + ko;
        Bh[0] = *(const u16x8*)(Wih_h + w0);
        Bl[0] = *(const u16x8*)(Wih_l + w0);
        Bh[1] = *(const u16x8*)(Wih_h + w1);
        Bl[1] = *(const u16x8*)(Wih_l + w1);
    };
    auto MMA = [&](u16x8 (&Ah)[2], u16x8 (&Al)[2], u16x8 (&Bh)[2], u16x8 (&Bl)[2]) {
        #pragma unroll
        for (int rt = 0; rt < 2; ++rt)
            #pragma unroll
            for (int cf = 0; cf < 2; ++cf) {
                mfma16(acc[rt][cf], Ah[rt], Bh[cf]);
                mfma16(acc[rt][cf], Ah[rt], Bl[cf]);
                mfma16(acc[rt][cf], Al[rt], Bh[cf]);
            }
    };

    LD(a0h, a0l, b0h, b0l, 0);
    #pragma unroll
    for (int ks = 0; ks < 10; ks += 2) {
        LD(a1h, a1l, b1h, b1l, ks + 1);
        MMA(a0h, a0l, b0h, b0l);
        if (ks + 2 < 10) LD(a0h, a0l, b0h, b0l, ks + 2);
        MMA(a1h, a1l, b1h, b1l);
    }

    #pragma unroll
    for (int rt = 0; rt < 2; ++rt) {
        long o0 = ((long)tloc * 2048 + colf0) * 256 + b0 + rt * 16 + (lane >> 4) * 4;
        long o1 = ((long)tloc * 2048 + colf1) * 256 + b0 + rt * 16 + (lane >> 4) * 4;
        *(f32x4*)(xgT + o0) = acc[rt][0];
        *(f32x4*)(xgT + o1) = acc[rt][1];
    }
}

__global__ __launch_bounds__(64) void xg_mfma(
    const u16* __restrict__ xh, const u16* __restrict__ xl,
    const u16* __restrict__ Wih_h, const u16* __restrict__ Wih_l,
    const float* __restrict__ bih, const float* __restrict__ bhh,
    float* __restrict__ xgT, int t0abs, int tstep)
{
    xg_job(blockIdx.x, threadIdx.x, xh, xl, Wih_h, Wih_l, bih, bhh, xgT, t0abs, tstep);
}

// ---------------------------------------------------------------------------
// Per-rblk-group grid barrier (32 blocks/group), r5..r9-verified.
// ---------------------------------------------------------------------------
__device__ __forceinline__ void group_bar(unsigned* cnt, unsigned* gen,
                                          unsigned nb, unsigned g)
{
    __syncthreads();
    if (threadIdx.x == 0) {
        unsigned old = __hip_atomic_fetch_add(cnt, 1u, __ATOMIC_RELEASE,
                                              __HIP_MEMORY_SCOPE_AGENT);
        if (old == nb - 1u) {
            __hip_atomic_store(cnt, 0u, __ATOMIC_RELAXED, __HIP_MEMORY_SCOPE_AGENT);
            __hip_atomic_store(gen, g + 1u, __ATOMIC_RELEASE, __HIP_MEMORY_SCOPE_AGENT);
        } else {
            while (__hip_atomic_load(gen, __ATOMIC_RELAXED, __HIP_MEMORY_SCOPE_AGENT) < g + 1u)
                __builtin_amdgcn_s_sleep(2);
            (void)__hip_atomic_load(gen, __ATOMIC_ACQUIRE, __HIP_MEMORY_SCOPE_AGENT);
        }
    }
    __syncthreads();
}

// ---------------------------------------------------------------------------
// lstm_persist (r11): r9-verified recurrence (waves 0-3, XCD-pinned barrier
// groups, per-step cst read/write — the 594us/chunk 4.87ms config) PLUS
// producer waves 4-7 that compute the NEXT chunk's xg tiles (xg_job) into a
// double-buffered xgT during barrier-stall idle cycles. All barriers are
// outside wid branches -> every wave executes the identical barrier sequence
// (deadlock-free by construction). Producers do q = ceil(J/1024/L) jobs/step.
// ---------------------------------------------------------------------------
struct NextXG {
    const u16* Wih_h; const u16* Wih_l;
    const float* bih; const float* bhh;
    float* dst; int t0abs; int tstep; int L;
};

__global__ __launch_bounds__(512) void lstm_persist(
    const float* __restrict__ xgT,
    const u16* __restrict__ Whh_h, const u16* __restrict__ Whh_l,
    u16* __restrict__ hAh, u16* __restrict__ hAl,
    u16* __restrict__ hBh, u16* __restrict__ hBl,
    float* __restrict__ cst,
    float* __restrict__ ex, long ex_bstride, int ex_t0, int ex_tstep,
    int ex_coff, int ex_final,
    unsigned* __restrict__ bars, int s0, int L,
    const u16* __restrict__ xh, const u16* __restrict__ xl,
    NextXG nx)
{
    const int gx   = blockIdx.x;
    const int rblk = gx & 7;          // XCD-pinned group (32 blocks, one XCD)
    const int cblk = gx >> 3;         // 0..31 col tile
    const int wid  = threadIdx.x >> 6;
    const int lane = threadIdx.x & 63;
    const int lr   = lane & 15;
    const int lk8  = (lane >> 4) * 8;
    const int b0   = rblk * 32;
    const int col  = cblk * 16 + lr;

    __shared__ u16 WH[64][520];
    __shared__ u16 WL[64][520];
    __shared__ f32x4 RED[3][64][8];

    for (int idx = threadIdx.x; idx < 64 * 64; idx += 512) {
        int rr = idx >> 6;
        int kk = (idx & 63) << 3;
        int g = rr >> 4, cc = rr & 15;
        long gro = (long)(g * HD + cblk * 16 + cc) * HD + kk;
        *(u16x8*)&WH[rr][kk] = *(const u16x8*)(Whh_h + gro);
        *(u16x8*)&WL[rr][kk] = *(const u16x8*)(Whh_l + gro);
    }
    __syncthreads();

    unsigned* bcnt = bars + rblk * 64;
    unsigned* bgen = bars + 512 + rblk * 64;
    unsigned gen = 0;
    const int ksbase = (wid & 3) * 4;

    // producer setup (waves 4-7)
    const long Jtot = (long)nx.L * 512;
    const int q = (nx.L > 0) ? (int)((Jtot + (long)1024 * L - 1) / ((long)1024 * L)) : 0;
    long jidx = (long)gx * 4 + (wid - 4);   // producer job id stream (wid>=4)

    for (int ti = 0; ti < L; ++ti) {
        const int s = s0 + ti;
        const u16* hih = (s & 1) ? hBh : hAh;
        const u16* hil = (s & 1) ? hBl : hAl;
        u16* hoh = (s & 1) ? hAh : hBh;
        u16* hol = (s & 1) ? hAl : hBl;

        f32x4 acc[2][4];
        if (wid < 4) {
            if (wid == 0) {
                #pragma unroll
                for (int rt = 0; rt < 2; ++rt)
                    #pragma unroll
                    for (int g = 0; g < 4; ++g) {
                        long o = ((long)ti * 2048 + g * HD + col) * 256
                                 + b0 + rt * 16 + (lane >> 4) * 4;
                        acc[rt][g] = __builtin_nontemporal_load((const f32x4*)(xgT + o));
                    }
            } else {
                #pragma unroll
                for (int rt = 0; rt < 2; ++rt)
                    #pragma unroll
                    for (int g = 0; g < 4; ++g) acc[rt][g] = f32x4{0.f, 0.f, 0.f, 0.f};
            }

            u16x8 Ah0[2], Al0[2], Bh0[4], Bl0[4];
            u16x8 Ah1[2], Al1[2], Bh1[4], Bl1[4];

            auto MMA = [&](u16x8 (&Ah)[2], u16x8 (&Al)[2], u16x8 (&Bh)[4], u16x8 (&Bl)[4]) {
                #pragma unroll
                for (int rt = 0; rt < 2; ++rt)
                    #pragma unroll
                    for (int g = 0; g < 4; ++g) {
                        mfma16(acc[rt][g], Ah[rt], Bh[g]);
                        mfma16(acc[rt][g], Ah[rt], Bl[g]);
                        mfma16(acc[rt][g], Al[rt], Bh[g]);
                    }
            };
            auto LD = [&](u16x8 (&Ah)[2], u16x8 (&Al)[2], u16x8 (&Bh)[4], u16x8 (&Bl)[4], int ks) {
                const int ko = ks * 32 + lk8;
                #pragma unroll
                for (int rt = 0; rt < 2; ++rt) {
                    long off = (long)(b0 + rt * 16 + lr) * HD + ko;
                    Ah[rt] = *(const u16x8*)(hih + off);
                    Al[rt] = *(const u16x8*)(hil + off);
                }
                #pragma unroll
                for (int g = 0; g < 4; ++g) {
                    Bh[g] = *(const u16x8*)&WH[g * 16 + lr][ko];
                    Bl[g] = *(const u16x8*)&WL[g * 16 + lr][ko];
                }
            };

            LD(Ah0, Al0, Bh0, Bl0, ksbase + 0);
            LD(Ah1, Al1, Bh1, Bl1, ksbase + 1);
            MMA(Ah0, Al0, Bh0, Bl0);
            LD(Ah0, Al0, Bh0, Bl0, ksbase + 2);
            MMA(Ah1, Al1, Bh1, Bl1);
            LD(Ah1, Al1, Bh1, Bl1, ksbase + 3);
            MMA(Ah0, Al0, Bh0, Bl0);
            MMA(Ah1, Al1, Bh1, Bl1);

            if (wid != 0) {
                #pragma unroll
                for (int rt = 0; rt < 2; ++rt)
                    #pragma unroll
                    for (int g = 0; g < 4; ++g)
                        RED[wid - 1][lane][rt * 4 + g] = acc[rt][g];
            }
        } else {
            // producer: bounded xg quota for the NEXT chunk (independent data)
            #pragma unroll 1
            for (int itq = 0; itq < q; ++itq) {
                if (jidx < Jtot) {
                    xg_job((int)jidx, lane, xh, xl, nx.Wih_h, nx.Wih_l,
                           nx.bih, nx.bhh, nx.dst, nx.t0abs, nx.tstep);
                    jidx += 1024;
                }
            }
        }
        __syncthreads();

        if (wid == 0) {
            #pragma unroll
            for (int w = 0; w < 3; ++w)
                #pragma unroll
                for (int rt = 0; rt < 2; ++rt)
                    #pragma unroll
                    for (int g = 0; g < 4; ++g)
                        acc[rt][g] += RED[w][lane][rt * 4 + g];

            const bool exw = (ex_final == -2) || (ex_final >= 0 && ti == ex_final);
            const int tt = ex_t0 + ex_tstep * ti;
            #pragma unroll
            for (int rt = 0; rt < 2; ++rt) {
                #pragma unroll
                for (int r = 0; r < 4; ++r) {
                    const int b = b0 + rt * 16 + (lane >> 4) * 4 + r;
                    const long hoff = (long)b * HD + col;
                    float iv = acc[rt][0][r];
                    float fv = acc[rt][1][r];
                    float gv = acc[rt][2][r];
                    float ov = acc[rt][3][r];
                    float cp = cst[hoff];
                    float si = 1.f / (1.f + expf(-iv));
                    float sf = 1.f / (1.f + expf(-fv));
                    float so = 1.f / (1.f + expf(-ov));
                    float cn = sf * cp + si * tanhf(gv);
                    float hn = so * tanhf(cn);
                    cst[hoff] = cn;
                    u16 hb = bf16_rte(hn);
                    hoh[hoff] = hb;
                    hol[hoff] = bf16_rte(hn - __builtin_bit_cast(float, (unsigned)hb << 16));
                    if (exw) ex[(long)b * ex_bstride + (long)tt * 1024 + ex_coff + col] = hn;
                }
            }
        }
        if (ti + 1 < L) { group_bar(bcnt, bgen, 32u, gen); ++gen; }
    }
}

// ---------------------------------------------------------------------------
// body_persist: r5-verified 1-wave fallback (inline phase 1), small-ws path.
// ---------------------------------------------------------------------------
__global__ __launch_bounds__(64) void body_persist(
    const u16* __restrict__ xh, const u16* __restrict__ xl,
    const u16* __restrict__ Wih_h, const u16* __restrict__ Wih_l,
    const u16* __restrict__ Whh_h, const u16* __restrict__ Whh_l,
    const float* __restrict__ bih, const float* __restrict__ bhh,
    u16* __restrict__ hAh, u16* __restrict__ hAl,
    u16* __restrict__ hBh, u16* __restrict__ hBl,
    float* __restrict__ cst, float* __restrict__ ex,
    unsigned* __restrict__ bars)
{
    const int gx   = blockIdx.x;
    const int xcd  = gx & 7, j = gx >> 3;
    const int cblk = xcd * 4 + (j & 3);
    const int rblk = j >> 2;
    const int lane = threadIdx.x;
    const int lr   = lane & 15;
    const int lk8  = (lane >> 4) * 8;
    const int b0   = rblk * 32;
    const int col  = cblk * 16 + lr;

    __shared__ u16 WH[64][520];
    __shared__ u16 WL[64][520];
    for (int idx = lane; idx < 64 * 64; idx += 64) {
        int rr = idx >> 6;
        int kk = (idx & 63) << 3;
        int g = rr >> 4, cc = rr & 15;
        long gro = (long)(g * HD + cblk * 16 + cc) * HD + kk;
        *(u16x8*)&WH[rr][kk] = *(const u16x8*)(Whh_h + gro);
        *(u16x8*)&WL[rr][kk] = *(const u16x8*)(Whh_l + gro);
    }
    __syncthreads();

    float bsum[4];
    #pragma unroll
    for (int g = 0; g < 4; ++g) bsum[g] = bih[g * HD + col] + bhh[g * HD + col];

    unsigned* bcnt = bars + rblk * 64;
    unsigned* bgen = bars + 512 + rblk * 64;
    unsigned gen = 0;

    for (int t = 1; t < 200; ++t) {
        const int s = 40 + t;
        const u16* hih = (s & 1) ? hBh : hAh;
        const u16* hil = (s & 1) ? hBl : hAl;
        u16* hoh = (s & 1) ? hAh : hBh;
        u16* hol = (s & 1) ? hAl : hBl;

        f32x4 acc[2][4];
        #pragma unroll
        for (int g = 0; g < 4; ++g) {
            acc[0][g] = f32x4{bsum[g], bsum[g], bsum[g], bsum[g]};
            acc[1][g] = f32x4{bsum[g], bsum[g], bsum[g], bsum[g]};
        }

        u16x8 Ah0[2], Al0[2], Bh0[4], Bl0[4];
        u16x8 Ah1[2], Al1[2], Bh1[4], Bl1[4];

        auto MMA = [&](u16x8 (&Ah)[2], u16x8 (&Al)[2], u16x8 (&Bh)[4], u16x8 (&Bl)[4]) {
            #pragma unroll
            for (int rt = 0; rt < 2; ++rt)
                #pragma unroll
                for (int g = 0; g < 4; ++g) {
                    mfma16(acc[rt][g], Ah[rt], Bh[g]);
                    mfma16(acc[rt][g], Ah[rt], Bl[g]);
                    mfma16(acc[rt][g], Al[rt], Bh[g]);
                }
        };
        {
            auto LD = [&](u16x8 (&Ah)[2], u16x8 (&Al)[2], u16x8 (&Bh)[4], u16x8 (&Bl)[4], int ks) {
                const int ko = ks * 32 + lk8;
                #pragma unroll
                for (int rt = 0; rt < 2; ++rt) {
                    long off = ((long)(b0 + rt * 16 + lr) * TDIM + (40 + t)) * 320 + ko;
                    Ah[rt] = *(const u16x8*)(xh + off);
                    Al[rt] = *(const u16x8*)(xl + off);
                }
                #pragma unroll
                for (int g = 0; g < 4; ++g) {
                    long off = (long)(g * HD + col) * 320 + ko;
                    Bh[g] = *(const u16x8*)(Wih_h + off);
                    Bl[g] = *(const u16x8*)(Wih_l + off);
                }
            };
            LD(Ah0, Al0, Bh0, Bl0, 0);
            #pragma unroll
            for (int ks = 0; ks < 10; ks += 2) {
                LD(Ah1, Al1, Bh1, Bl1, ks + 1);
                MMA(Ah0, Al0, Bh0, Bl0);
                if (ks + 2 < 10) LD(Ah0, Al0, Bh0, Bl0, ks + 2);
                MMA(Ah1, Al1, Bh1, Bl1);
            }
        }
        {
            auto LD = [&](u16x8 (&Ah)[2], u16x8 (&Al)[2], u16x8 (&Bh)[4], u16x8 (&Bl)[4], int ks) {
                const int ko = ks * 32 + lk8;
                #pragma unroll
                for (int rt = 0; rt < 2; ++rt) {
                    long off = (long)(b0 + rt * 16 + lr) * HD + ko;
                    Ah[rt] = *(const u16x8*)(hih + off);
                    Al[rt] = *(const u16x8*)(hil + off);
                }
                #pragma unroll
                for (int g = 0; g < 4; ++g) {
                    Bh[g] = *(const u16x8*)&WH[g * 16 + lr][ko];
                    Bl[g] = *(const u16x8*)&WL[g * 16 + lr][ko];
                }
            };
            LD(Ah0, Al0, Bh0, Bl0, 0);
            #pragma unroll
            for (int ks = 0; ks < 16; ks += 2) {
                LD(Ah1, Al1, Bh1, Bl1, ks + 1);
                MMA(Ah0, Al0, Bh0, Bl0);
                if (ks + 2 < 16) LD(Ah0, Al0, Bh0, Bl0, ks + 2);
                MMA(Ah1, Al1, Bh1, Bl1);
            }
        }
        float* exw = (t == 199) ? ex : (float*)nullptr;
        #pragma unroll
        for (int rt = 0; rt < 2; ++rt) {
            #pragma unroll
            for (int r = 0; r < 4; ++r) {
                const int b = b0 + rt * 16 + (lane >> 4) * 4 + r;
                const long hoff = (long)b * HD + col;
                float iv = acc[rt][0][r];
                float fv = acc[rt][1][r];
                float gv = acc[rt][2][r];
                float ov = acc[rt][3][r];
                float cp = cst[hoff];
                float si = 1.f / (1.f + expf(-iv));
                float sf = 1.f / (1.f + expf(-fv));
                float so = 1.f / (1.f + expf(-ov));
                float cn = sf * cp + si * tanhf(gv);
                float hn = so * tanhf(cn);
                cst[hoff] = cn;
                u16 hb = bf16_rte(hn);
                hoh[hoff] = hb;
                hol[hoff] = bf16_rte(hn - __builtin_bit_cast(float, (unsigned)hb << 16));
                if (exw) exw[(long)b * 1024 + col] = hn;
            }
        }
        group_bar(bcnt, bgen, 32u, gen);
        ++gen;
    }
}

// ---------------------------------------------------------------------------
// Generic bf16-split MFMA GEMM (epilogue): r3-verified.
// ---------------------------------------------------------------------------
template<int ACT>
__global__ __launch_bounds__(64) void mfma_gemm(
    const u16* __restrict__ Ah_, const u16* __restrict__ Al_,
    const u16* __restrict__ Wh_, const u16* __restrict__ Wl_,
    const float* __restrict__ bias, float* __restrict__ C,
    int ldc, int K, int n16)
{
    const int gx = blockIdx.x;
    const int nblk = gx % n16, mblk = gx / n16;
    const int lane = threadIdx.x;
    const int lr = lane & 15, lk8 = (lane >> 4) * 8;
    const int b0 = mblk * 32, col = nblk * 16 + lr;

    f32x4 acc[2] = {f32x4{0,0,0,0}, f32x4{0,0,0,0}};
    u16x8 A0[2], L0[2], A1[2], L1[2];
    u16x8 B0, M0, B1, M1;

    auto LD = [&](u16x8 (&A)[2], u16x8 (&L)[2], u16x8& B, u16x8& M, int ks) {
        const int ko = ks * 32 + lk8;
        #pragma unroll
        for (int rt = 0; rt < 2; ++rt) {
            long off = (long)(b0 + rt * 16 + lr) * K + ko;
            A[rt] = *(const u16x8*)(Ah_ + off);
            L[rt] = *(const u16x8*)(Al_ + off);
        }
        long woff = (long)col * K + ko;
        B = *(const u16x8*)(Wh_ + woff);
        M = *(const u16x8*)(Wl_ + woff);
    };
    auto MMA = [&](u16x8 (&A)[2], u16x8 (&L)[2], u16x8& B, u16x8& M) {
        #pragma unroll
        for (int rt = 0; rt < 2; ++rt) {
            mfma16(acc[rt], A[rt], B);
            mfma16(acc[rt], A[rt], M);
            mfma16(acc[rt], L[rt], B);
        }
    };

    const int NS = K >> 5;
    LD(A0, L0, B0, M0, 0);
    for (int ks = 0; ks < NS; ks += 2) {
        if (ks + 1 < NS) LD(A1, L1, B1, M1, ks + 1);
        MMA(A0, L0, B0, M0);
        if (ks + 2 < NS) LD(A0, L0, B0, M0, ks + 2);
        if (ks + 1 < NS) MMA(A1, L1, B1, M1);
    }

    float bs = bias ? bias[col] : 0.f;
    #pragma unroll
    for (int rt = 0; rt < 2; ++rt)
        #pragma unroll
        for (int r = 0; r < 4; ++r) {
            int m = b0 + rt * 16 + (lane >> 4) * 4 + r;
            float v = acc[rt][r] + bs;
            if (ACT == 1) v = tanhf(v);
            C[(long)m * ldc + col] = v;
        }
}

// ---------------------------------------------------------------------------
// Legacy fp32 path (tiny workspace fallback) — r1-verified.
// ---------------------------------------------------------------------------
template<int BB>
__global__ __launch_bounds__(256) void lstm_step(
    const float* __restrict__ x,
    const float* __restrict__ Wih0, const float* __restrict__ Whh0,
    const float* __restrict__ bih0, const float* __restrict__ bhh0,
    const float* __restrict__ hin0, float* __restrict__ hnew0, float* __restrict__ cst0,
    float* __restrict__ ex0, int exs0, int tx0,
    const float* __restrict__ Wih1, const float* __restrict__ Whh1,
    const float* __restrict__ bih1, const float* __restrict__ bhh1,
    const float* __restrict__ hin1, float* __restrict__ hnew1, float* __restrict__ cst1,
    float* __restrict__ ex1, int exs1, int tx1)
{
    const int dir = blockIdx.z;
    const float* Wih = dir ? Wih1 : Wih0;
    const float* Whh = dir ? Whh1 : Whh0;
    const float* bih = dir ? bih1 : bih0;
    const float* bhh = dir ? bhh1 : bhh0;
    const float* hin = dir ? hin1 : hin0;
    float* hnew = dir ? hnew1 : hnew0;
    float* cst  = dir ? cst1  : cst0;
    float* ex   = dir ? ex1   : ex0;
    const int exs = dir ? exs1 : exs0;
    const int tx  = dir ? tx1  : tx0;

    const int bblk = blockIdx.x, kblk = blockIdx.y;
    const int tid = threadIdx.x;
    const int j  = tid & 15;
    const int ty = tid >> 4;
    const int k  = kblk * 16 + j;
    constexpr int RB = BB / 16;

    __shared__ float As[BB][33];
    __shared__ float Bs[32][65];

    float acc[RB][4];
    #pragma unroll
    for (int r = 0; r < RB; ++r)
        #pragma unroll
        for (int q = 0; q < 4; ++q) acc[r][q] = 0.f;

    const int lb = tid >> 5, lk = tid & 31;

    for (int kb = 0; kb < INDIM; kb += 32) {
        #pragma unroll
        for (int it = 0; it < BB/8; ++it) {
            int b = lb + it*8;
            int i = kb + lk;
            As[b][lk] = (i < INDIM) ? x[((bblk*BB + b)*TDIM + tx)*INDIM + i] : 0.f;
        }
        #pragma unroll
        for (int it = 0; it < 8; ++it) {
            int col = lb + it*8;
            int g = (col >> 4)*HD + kblk*16 + (col & 15);
            int i = kb + lk;
            Bs[lk][col] = (i < INDIM) ? Wih[g*INDIM + i] : 0.f;
        }
        __syncthreads();
        #pragma unroll
        for (int kk = 0; kk < 32; ++kk) {
            float a_[RB], b_[4];
            #pragma unroll
            for (int r = 0; r < RB; ++r) a_[r] = As[ty*RB + r][kk];
            #pragma unroll
            for (int q = 0; q < 4; ++q) b_[q] = Bs[kk][q*16 + j];
            #pragma unroll
            for (int r = 0; r < RB; ++r)
                #pragma unroll
                for (int q = 0; q < 4; ++q) acc[r][q] += a_[r]*b_[q];
        }
        __syncthreads();
    }
    for (int kb = 0; kb < HD; kb += 32) {
        #pragma unroll
        for (int it = 0; it < BB/8; ++it) {
            int b = lb + it*8;
            As[b][lk] = hin[(bblk*BB + b)*HD + kb + lk];
        }
        #pragma unroll
        for (int it = 0; it < 8; ++it) {
            int col = lb + it*8;
            int g = (col >> 4)*HD + kblk*16 + (col & 15);
            Bs[lk][col] = Whh[g*HD + kb + lk];
        }
        __syncthreads();
        #pragma unroll
        for (int kk = 0; kk < 32; ++kk) {
            float a_[RB], b_[4];
            #pragma unroll
            for (int r = 0; r < RB; ++r) a_[r] = As[ty*RB + r][kk];
            #pragma unroll
            for (int q = 0; q < 4; ++q) b_[q] = Bs[kk][q*16 + j];
            #pragma unroll
            for (int r = 0; r < RB; ++r)
                #pragma unroll
                for (int q = 0; q < 4; ++q) acc[r][q] += a_[r]*b_[q];
        }
        __syncthreads();
    }
    float bsum[4];
    #pragma unroll
    for (int q = 0; q < 4; ++q) bsum[q] = bih[q*HD + k] + bhh[q*HD + k];
    #pragma unroll
    for (int r = 0; r < RB; ++r) {
        int gb = bblk*BB + ty*RB + r;
        float iv = acc[r][0] + bsum[0];
        float fv = acc[r][1] + bsum[1];
        float gv = acc[r][2] + bsum[2];
        float ov = acc[r][3] + bsum[3];
        float cprev = cst[gb*HD + k];
        float si = 1.f/(1.f + expf(-iv));
        float sf = 1.f/(1.f + expf(-fv));
        float so = 1.f/(1.f + expf(-ov));
        float cn = sf*cprev + si*tanhf(gv);
        float hn = so*tanhf(cn);
        cst[gb*HD + k]  = cn;
        hnew[gb*HD + k] = hn;
        if (ex) ex[gb*exs + k] = hn;
    }
}

template<int ACT>
__global__ __launch_bounds__(256) void gemm_bias_act(
    const float* __restrict__ A, int lda,
    const float* __restrict__ W,
    const float* __restrict__ bias,
    float* __restrict__ C, int ldc,
    int K)
{
    const int mblk = blockIdx.x, nblk = blockIdx.y;
    const int tid = threadIdx.x;
    const int txd = tid & 15, ty = tid >> 4;
    __shared__ float As[32][33];
    __shared__ float Bs[32][65];
    float acc[2][4] = {{0.f,0.f,0.f,0.f},{0.f,0.f,0.f,0.f}};
    const int lb = tid >> 5, lk = tid & 31;

    for (int kb = 0; kb < K; kb += 32) {
        #pragma unroll
        for (int it = 0; it < 4; ++it) {
            int r = lb + it*8;
            As[r][lk] = A[(mblk*32 + r)*lda + kb + lk];
        }
        #pragma unroll
        for (int it = 0; it < 8; ++it) {
            int col = lb + it*8;
            Bs[lk][col] = W[(nblk*64 + col)*K + kb + lk];
        }
        __syncthreads();
        #pragma unroll
        for (int kk = 0; kk < 32; ++kk) {
            float a0 = As[ty*2 + 0][kk], a1 = As[ty*2 + 1][kk];
            float b_[4];
            #pragma unroll
            for (int q = 0; q < 4; ++q) b_[q] = Bs[kk][q*16 + txd];
            #pragma unroll
            for (int q = 0; q < 4; ++q) { acc[0][q] += a0*b_[q]; acc[1][q] += a1*b_[q]; }
        }
        __syncthreads();
    }
    #pragma unroll
    for (int r = 0; r < 2; ++r) {
        int m = mblk*32 + ty*2 + r;
        #pragma unroll
        for (int q = 0; q < 4; ++q) {
            int n = nblk*64 + q*16 + txd;
            float v = acc[r][q] + (bias ? bias[n] : 0.f);
            if (ACT == 1) v = tanhf(v);
            C[m*ldc + n] = v;
        }
    }
}

// ---------------------------------------------------------------------------
// attention softmax/context + small epilogue kernels
// ---------------------------------------------------------------------------
__global__ __launch_bounds__(256) void attn_ctx(
    const float* __restrict__ title_out,
    const float* __restrict__ u,
    const float* __restrict__ bilb,
    float* __restrict__ attn_in)
{
    int b = blockIdx.x;
    int tid = threadIdx.x;
    __shared__ float uL[1024];
    __shared__ float sc[40];
    for (int e = tid; e < 1024; e += 256) uL[e] = u[b*1024 + e];
    __syncthreads();
    int wave = tid >> 6, lane = tid & 63;
    for (int t = wave*10; t < wave*10 + 10; ++t) {
        const float* row = title_out + (b*40 + t)*1024;
        float s = 0.f;
        for (int e = lane; e < 1024; e += 64) s += row[e]*uL[e];
        #pragma unroll
        for (int off = 32; off > 0; off >>= 1) s += __shfl_down(s, off, 64);
        if (lane == 0) sc[t] = s + bilb[0];
    }
    __syncthreads();
    if (tid < 64) {
        float v = (tid < 40) ? sc[tid] : -1e30f;
        float m = v;
        #pragma unroll
        for (int off = 32; off > 0; off >>= 1) m = fmaxf(m, __shfl_xor(m, off, 64));
        float e = (tid < 40) ? expf(v - m) : 0.f;
        float ssum = e;
        #pragma unroll
        for (int off = 32; off > 0; off >>= 1) ssum += __shfl_xor(ssum, off, 64);
        if (tid < 40) sc[tid] = e / ssum;
    }
    __syncthreads();
    for (int e = tid; e < 1024; e += 256) {
        float a = 0.f;
        #pragma unroll
        for (int t = 0; t < 40; ++t) a += sc[t]*title_out[(b*40 + t)*1024 + e];
        attn_in[b*2048 + e] = a;
    }
}

__global__ void copy_rows(const float* __restrict__ src, int ss,
                          float* __restrict__ dst, int ds, int n)
{
    int b = blockIdx.x;
    for (int e = threadIdx.x; e < n; e += blockDim.x) dst[b*ds + e] = src[b*ss + e];
}

__global__ __launch_bounds__(64) void final_cls(
    const float* __restrict__ ch,
    const float* __restrict__ clsW,
    const float* __restrict__ clsb,
    float* __restrict__ out)
{
    int b = blockIdx.x*64 + threadIdx.x;
    float o[4];
    #pragma unroll
    for (int n = 0; n < 4; ++n) {
        float s = clsb[n];
        for (int jj = 0; jj < 512; ++jj) s += ch[b*512 + jj]*clsW[n*512 + jj];
        o[n] = s;
    }
    float m = fmaxf(fmaxf(o[0], o[1]), fmaxf(o[2], o[3]));
    float e0 = expf(o[0]-m), e1 = expf(o[1]-m), e2 = expf(o[2]-m), e3 = expf(o[3]-m);
    float s = e0 + e1 + e2 + e3;
    out[b*4+0] = e0/s; out[b*4+1] = e1/s; out[b*4+2] = e2/s; out[b*4+3] = e3/s;
}

// ---------------------------------------------------------------------------
extern "C" void kernel_launch(void* const* d_in, const int* in_sizes, int n_in,
                              void* d_out, int out_size, void* d_ws, size_t ws_size,
                              hipStream_t stream) {
    const float* x     = (const float*)d_in[0];
    const float* tWih  = (const float*)d_in[1];
    const float* tWhh  = (const float*)d_in[2];
    const float* tbih  = (const float*)d_in[3];
    const float* tbhh  = (const float*)d_in[4];
    const float* bWih  = (const float*)d_in[5];
    const float* bWhh  = (const float*)d_in[6];
    const float* bbih  = (const float*)d_in[7];
    const float* bbhh  = (const float*)d_in[8];
    const float* bilW  = (const float*)d_in[9];
    const float* bilb  = (const float*)d_in[10];
    const float* attnW = (const float*)d_in[11];
    const float* attnb = (const float*)d_in[12];
    const float* decW  = (const float*)d_in[13];
    const float* decb  = (const float*)d_in[14];
    const float* clsW  = (const float*)d_in[15];
    const float* clsb  = (const float*)d_in[16];

    char* base = (char*)d_ws;
    size_t off = 0;
    auto carve = [&](size_t bytes) -> void* {
        void* r = base + off; off += (bytes + 255) & ~(size_t)255; return r;
    };

    u16* hA0h = (u16*)carve(BATCH*HD*2);
    u16* hA0l = (u16*)carve(BATCH*HD*2);
    u16* hA1h = (u16*)carve(BATCH*HD*2);
    u16* hA1l = (u16*)carve(BATCH*HD*2);
    float* c0 = (float*)carve(BATCH*HD*4);
    float* c1 = (float*)carve(BATCH*HD*4);
    unsigned* bars = (unsigned*)carve(32*4096);
    size_t zero_bytes = off;
    u16* hB0h = (u16*)carve(BATCH*HD*2);
    u16* hB0l = (u16*)carve(BATCH*HD*2);
    u16* hB1h = (u16*)carve(BATCH*HD*2);
    u16* hB1l = (u16*)carve(BATCH*HD*2);
    u16* xh = (u16*)carve((size_t)BATCH*TDIM*320*2);
    u16* xl = (u16*)carve((size_t)BATCH*TDIM*320*2);
    u16* tW0ih_h = (u16*)carve(2048*320*2); u16* tW0ih_l = (u16*)carve(2048*320*2);
    u16* tW1ih_h = (u16*)carve(2048*320*2); u16* tW1ih_l = (u16*)carve(2048*320*2);
    u16* bW0ih_h = (u16*)carve(2048*320*2); u16* bW0ih_l = (u16*)carve(2048*320*2);
    u16* bW1ih_h = (u16*)carve(2048*320*2); u16* bW1ih_l = (u16*)carve(2048*320*2);
    u16* tW0hh_h = (u16*)carve(2048*512*2); u16* tW0hh_l = (u16*)carve(2048*512*2);
    u16* tW1hh_h = (u16*)carve(2048*512*2); u16* tW1hh_l = (u16*)carve(2048*512*2);
    u16* bW0hh_h = (u16*)carve(2048*512*2); u16* bW0hh_l = (u16*)carve(2048*512*2);
    u16* bW1hh_h = (u16*)carve(2048*512*2); u16* bW1hh_l = (u16*)carve(2048*512*2);
    float* title_out = (float*)carve((size_t)BATCH*40*1024*4);
    float* body_last = (float*)carve((size_t)BATCH*1024*4);
    float* u_buf     = (float*)carve((size_t)BATCH*1024*4);
    float* attn_in   = (float*)carve((size_t)BATCH*2048*4);
    float* out_cat   = (float*)carve((size_t)BATCH*2048*4);
    float* ch        = (float*)carve((size_t)BATCH*512*4);
    u16* bl_h = (u16*)carve((size_t)BATCH*1024*2); u16* bl_l = (u16*)carve((size_t)BATCH*1024*2);
    u16* ai_h = (u16*)carve((size_t)BATCH*2048*2); u16* ai_l = (u16*)carve((size_t)BATCH*2048*2);
    u16* oc_h = (u16*)carve((size_t)BATCH*2048*2); u16* oc_l = (u16*)carve((size_t)BATCH*2048*2);
    u16* bilW_h  = (u16*)carve(1024*1024*2); u16* bilW_l  = (u16*)carve(1024*1024*2);
    u16* attnW_h = (u16*)carve((size_t)1024*2048*2); u16* attnW_l = (u16*)carve((size_t)1024*2048*2);
    u16* decW_h  = (u16*)carve((size_t)512*2048*2);  u16* decW_l  = (u16*)carve((size_t)512*2048*2);
    size_t need = off;

    const size_t SLAB_BYTES = (size_t)2048 * 256 * 4;
    float* xgBase = (float*)(base + off);
    int C = 0;
    if (ws_size > need) {
        size_t nslab = (ws_size - need) / SLAB_BYTES;
        size_t half = nslab / 2;
        C = (int)(half > 50 ? 50 : half);
    }
    const bool xg_ok = (C >= 10);
    const long SLABF = 2048L * 256;
    auto buf = [&](int i) { return xgBase + (size_t)(i & 1) * C * SLABF; };

    if (ws_size >= need) {
        hipMemsetAsync(d_ws, 0, zero_bytes, stream);

        auto SPLIT = [&](const float* s, u16* h, u16* l, long rows, int kin, int kout) {
            long n = rows * (long)kout;
            split_pad<<<dim3((unsigned)((n + 255) / 256)), 256, 0, stream>>>(s, h, l, (int)rows, kin, kout);
        };
        SPLIT(x, xh, xl, (long)BATCH*TDIM, INDIM, 320);
        SPLIT(tWih,               tW0ih_h, tW0ih_l, 2048, INDIM, 320);
        SPLIT(tWih + 2048*INDIM,  tW1ih_h, tW1ih_l, 2048, INDIM, 320);
        SPLIT(bWih,               bW0ih_h, bW0ih_l, 2048, INDIM, 320);
        SPLIT(bWih + 2048*INDIM,  bW1ih_h, bW1ih_l, 2048, INDIM, 320);
        SPLIT(tWhh,               tW0hh_h, tW0hh_l, 2048, HD, HD);
        SPLIT(tWhh + 2048*HD,     tW1hh_h, tW1hh_l, 2048, HD, HD);
        SPLIT(bWhh,               bW0hh_h, bW0hh_l, 2048, HD, HD);
        SPLIT(bWhh + 2048*HD,     bW1hh_h, bW1hh_l, 2048, HD, HD);
        SPLIT(bilW,  bilW_h,  bilW_l,  1024, 1024, 1024);
        SPLIT(attnW, attnW_h, attnW_l, 1024, 2048, 2048);
        SPLIT(decW,  decW_h,  decW_l,  512,  2048, 2048);

        if (xg_ok) {
            // ---- build chunk descriptor list ----
            struct PD {
                NextXG xg;
                const u16 *Whh_h, *Whh_l;
                u16 *hAh, *hAl, *hBh, *hBl;
                float* cst;
                float* ex; long exb; int ext0, extstep, excoff, exfinal;
                int s0, L;
            };
            PD d[32]; int nd = 0;
            for (int tb = 0; tb < 40; tb += C) {           // title dir0
                int L = (C < 40 - tb) ? C : (40 - tb);
                d[nd++] = { { tW0ih_h, tW0ih_l, tbih, tbhh, nullptr, tb, 1, L },
                            tW0hh_h, tW0hh_l, hA0h, hA0l, hB0h, hB0l, c0,
                            title_out, 40*1024, tb, 1, 0, -2, tb, L };
            }
            for (int tb = 0; tb < 40; tb += C) {           // title dir1
                int L = (C < 40 - tb) ? C : (40 - tb);
                d[nd++] = { { tW1ih_h, tW1ih_l, tbih + 2048, tbhh + 2048, nullptr, 39 - tb, -1, L },
                            tW1hh_h, tW1hh_l, hA1h, hA1l, hB1h, hB1l, c1,
                            title_out, 40*1024, 39 - tb, -1, 512, -2, tb, L };
            }
            const int body_idx = nd;
            for (int tb = 1; tb < 200; tb += C) {          // body fwd
                int L = (C < 200 - tb) ? C : (200 - tb);
                bool last = (tb + L == 200);
                d[nd++] = { { bW0ih_h, bW0ih_l, bbih, bbhh, nullptr, 40 + tb, 1, L },
                            bW0hh_h, bW0hh_l, hA0h, hA0l, hB0h, hB0l, c0,
                            body_last, 1024, 0, 0, 0, last ? (L - 1) : -1, 40 + tb, L };
            }

            // chunk 0's xg: standalone (producers fill all subsequent chunks)
            xg_mfma<<<dim3((unsigned)(d[0].xg.L * 512)), 64, 0, stream>>>(
                xh, xl, d[0].xg.Wih_h, d[0].xg.Wih_l, d[0].xg.bih, d[0].xg.bhh,
                buf(0), d[0].xg.t0abs, d[0].xg.tstep);

            for (int i = 0; i < nd; ++i) {
                if (i == body_idx) {
                    // body t=0: fwd + single bwd step (tx=239) — reads title
                    // final states in hA0/hA1, writes hB0/hB1 (+body_last hi)
                    StepDir F = { bW0ih_h, bW0ih_l, bW0hh_h, bW0hh_l, bbih, bbhh,
                                  hA0h, hA0l, hB0h, hB0l, c0, (float*)nullptr, 0, 40 };
                    StepDir R = { bW1ih_h, bW1ih_l, bW1hh_h, bW1hh_l, bbih + 2048, bbhh + 2048,
                                  hA1h, hA1l, hB1h, hB1l, c1, body_last + 512, 1024, 239 };
                    step_mfma<<<dim3(256,1,2), 64, 0, stream>>>(xh, xl, F, R);
                }
                NextXG nx = { nullptr, nullptr, nullptr, nullptr, nullptr, 0, 0, 0 };
                if (i + 1 < nd) { nx = d[i + 1].xg; nx.dst = buf(i + 1); }
                lstm_persist<<<dim3(256), 512, 0, stream>>>(
                    buf(i), d[i].Whh_h, d[i].Whh_l,
                    d[i].hAh, d[i].hAl, d[i].hBh, d[i].hBl, d[i].cst,
                    d[i].ex, d[i].exb, d[i].ext0, d[i].extstep, d[i].excoff, d[i].exfinal,
                    bars + (size_t)i * 1024, d[i].s0, d[i].L,
                    xh, xl, nx);
            }
        } else {
            // ---- fallback: r3/r5-verified step loop + 1-wave body persist ----
            for (int t = 0; t < 40; ++t) {
                bool odd = t & 1;
                StepDir A = { tW0ih_h, tW0ih_l, tW0hh_h, tW0hh_l, tbih, tbhh,
                              odd?hB0h:hA0h, odd?hB0l:hA0l, odd?hA0h:hB0h, odd?hA0l:hB0l,
                              c0, title_out + (size_t)t*1024, 40*1024, t };
                StepDir B = { tW1ih_h, tW1ih_l, tW1hh_h, tW1hh_l, tbih + 2048, tbhh + 2048,
                              odd?hB1h:hA1h, odd?hB1l:hA1l, odd?hA1h:hB1h, odd?hA1l:hB1l,
                              c1, title_out + (size_t)(39 - t)*1024 + 512, 40*1024, 39 - t };
                step_mfma<<<dim3(256,1,2), 64, 0, stream>>>(xh, xl, A, B);
            }
            {
                StepDir F = { bW0ih_h, bW0ih_l, bW0hh_h, bW0hh_l, bbih, bbhh,
                              hA0h, hA0l, hB0h, hB0l, c0, (float*)nullptr, 0, 40 };
                StepDir R = { bW1ih_h, bW1ih_l, bW1hh_h, bW1hh_l, bbih + 2048, bbhh + 2048,
                              hA1h, hA1l, hB1h, hB1l, c1, body_last + 512, 1024, 239 };
                step_mfma<<<dim3(256,1,2), 64, 0, stream>>>(xh, xl, F, R);
            }
            body_persist<<<dim3(256), 64, 0, stream>>>(
                xh, xl, bW0ih_h, bW0ih_l, bW0hh_h, bW0hh_l, bbih, bbhh,
                hA0h, hA0l, hB0h, hB0l, c0, body_last, bars);
        }

        // ---- attention + classifier (MFMA gemms, verified) ----
        SPLIT(body_last, bl_h, bl_l, 256, 1024, 1024);
        mfma_gemm<0><<<dim3(8*64), 64, 0, stream>>>(bl_h, bl_l, bilW_h, bilW_l,
                                                    (const float*)nullptr, u_buf, 1024, 1024, 64);
        attn_ctx<<<256, 256, 0, stream>>>(title_out, u_buf, bilb, attn_in);
        copy_rows<<<256, 256, 0, stream>>>(body_last, 1024, attn_in + 1024, 2048, 1024);
        copy_rows<<<256, 256, 0, stream>>>(title_out + 39*1024, 40*1024, out_cat, 2048, 1024);
        SPLIT(attn_in, ai_h, ai_l, 256, 2048, 2048);
        mfma_gemm<1><<<dim3(8*64), 64, 0, stream>>>(ai_h, ai_l, attnW_h, attnW_l,
                                                    attnb, out_cat + 1024, 2048, 2048, 64);
        SPLIT(out_cat, oc_h, oc_l, 256, 2048, 2048);
        mfma_gemm<0><<<dim3(8*32), 64, 0, stream>>>(oc_h, oc_l, decW_h, decW_l,
                                                    decb, ch, 512, 2048, 32);
        final_cls<<<4, 64, 0, stream>>>(ch, clsW, clsb, (float*)d_out);
    } else {
        // ================= legacy fp32 fallback =================
        float* p = (float*)d_ws;
        float* lhA0 = p; p += BATCH*HD;
        float* lc0  = p; p += BATCH*HD;
        float* lhA1 = p; p += BATCH*HD;
        float* lc1  = p; p += BATCH*HD;
        float* lhB0 = p; p += BATCH*HD;
        float* lhB1 = p; p += BATCH*HD;
        float* l_title = p; p += (size_t)BATCH*40*1024;
        float* l_blast = p; p += BATCH*1024;
        float* l_u     = p; p += BATCH*1024;
        float* l_ain   = p; p += BATCH*2048;
        float* l_ocat  = p; p += BATCH*2048;
        float* l_ch    = p; p += BATCH*512;

        hipMemsetAsync(lhA0, 0, (size_t)4*BATCH*HD*sizeof(float), stream);
        const float* tWih1 = tWih + 2048*INDIM;
        const float* tWhh1 = tWhh + 2048*HD;
        const float* bWih1 = bWih + 2048*INDIM;
        const float* bWhh1 = bWhh + 2048*HD;

        for (int t = 0; t < 40; ++t) {
            float* hi0 = (t & 1) ? lhB0 : lhA0;
            float* ho0 = (t & 1) ? lhA0 : lhB0;
            float* hi1 = (t & 1) ? lhB1 : lhA1;
            float* ho1 = (t & 1) ? lhA1 : lhB1;
            lstm_step<64><<<dim3(4,32,2), 256, 0, stream>>>(
                x, tWih, tWhh, tbih, tbhh, hi0, ho0, lc0,
                l_title + t*1024, 40*1024, t,
                tWih1, tWhh1, tbih + 2048, tbhh + 2048, hi1, ho1, lc1,
                l_title + (39 - t)*1024 + 512, 40*1024, 39 - t);
        }
        lstm_step<64><<<dim3(4,32,2), 256, 0, stream>>>(
            x, bWih, bWhh, bbih, bbhh, lhA0, lhB0, lc0, (float*)nullptr, 0, 40,
            bWih1, bWhh1, bbih + 2048, bbhh + 2048, lhA1, lhB1, lc1, l_blast + 512, 1024, 239);
        for (int t = 1; t < 200; ++t) {
            int s = 40 + t;
            float* hi = (s & 1) ? lhB0 : lhA0;
            float* ho = (s & 1) ? lhA0 : lhB0;
            float* exp_ = (t == 199) ? l_blast : (float*)nullptr;
            lstm_step<32><<<dim3(8,32,1), 256, 0, stream>>>(
                x, bWih, bWhh, bbih, bbhh, hi, ho, lc0, exp_, 1024, 40 + t,
                nullptr, nullptr, nullptr, nullptr, nullptr, nullptr, nullptr,
                (float*)nullptr, 0, 0);
        }
        gemm_bias_act<0><<<dim3(8,16), 256, 0, stream>>>(l_blast, 1024, bilW, nullptr, l_u, 1024, 1024);
        attn_ctx<<<256, 256, 0, stream>>>(l_title, l_u, bilb, l_ain);
        copy_rows<<<256, 256, 0, stream>>>(l_blast, 1024, l_ain + 1024, 2048, 1024);
        copy_rows<<<256, 256, 0, stream>>>(l_title + 39*1024, 40*1024, l_ocat, 2048, 1024);
        gemm_bias_act<1><<<dim3(8,16), 256, 0, stream>>>(l_ain, 2048, attnW, attnb, l_ocat + 1024, 2048, 2048);
        gemm_bias_act<0><<<dim3(8,8), 256, 0, stream>>>(l_ocat, 2048, decW, decb, l_ch, 512, 2048);
        final_cls<<<4, 64, 0, stream>>>(l_ch, clsW, clsb, (float*)d_out);
    }
}

// Round 12
// 4798.019 us; speedup vs baseline: 1.1194x; 1.1194x over previous
//
#include <hip/hip_runtime.h>
#include <math.h>

#define HD    512
#define BATCH 256
#define TDIM  240
#define INDIM 300

typedef unsigned short u16;
typedef u16   u16x8 __attribute__((ext_vector_type(8)));
typedef float f32x4 __attribute__((ext_vector_type(4)));

// ---------------------------------------------------------------------------
// bf16 split: v = hi + lo (RTE). 3-term MFMA product -> ~2^-17 rel error.
// ---------------------------------------------------------------------------
__device__ __forceinline__ u16 bf16_rte(float v) {
    unsigned u = __builtin_bit_cast(unsigned, v);
    unsigned r = (u + 0x7FFFu + ((u >> 16) & 1u)) >> 16;
    return (u16)r;
}

__device__ __forceinline__ void mfma16(f32x4& d, u16x8 a, u16x8 b) {
    asm("v_mfma_f32_16x16x32_bf16 %0, %1, %2, %0" : "+v"(d) : "v"(a), "v"(b));
}

__global__ __launch_bounds__(256) void split_pad(
    const float* __restrict__ src, u16* __restrict__ hi, u16* __restrict__ lo,
    int rows, int kin, int kout)
{
    long i = (long)blockIdx.x * 256 + threadIdx.x;
    if (i >= (long)rows * kout) return;
    int r = (int)(i / kout);
    int k = (int)(i - (long)r * kout);
    float v = (k < kin) ? src[(long)r * kin + k] : 0.f;
    u16 h = bf16_rte(v);
    float hf = __builtin_bit_cast(float, (unsigned)h << 16);
    hi[i] = h;
    lo[i] = bf16_rte(v - hf);
}

// fused variant: 12 jobs in one launch (identical per-element math)
struct SJob { const float* src; u16* hi; u16* lo; int kin; int kout; };
struct SParams { SJob j[12]; long cum[13]; };

__global__ __launch_bounds__(256) void split_all(SParams P)
{
    long gid = (long)blockIdx.x * 256 + threadIdx.x;
    if (gid >= P.cum[12]) return;
    int sgi = 0;
    #pragma unroll
    for (int k = 1; k < 12; ++k) if (gid >= P.cum[k]) sgi = k;
    const SJob& J = P.j[sgi];
    long i = gid - P.cum[sgi];
    int r = (int)(i / J.kout);
    int k = (int)(i - (long)r * J.kout);
    float v = (k < J.kin) ? J.src[(long)r * J.kin + k] : 0.f;
    u16 h = bf16_rte(v);
    float hf = __builtin_bit_cast(float, (unsigned)h << 16);
    J.hi[i] = h;
    J.lo[i] = bf16_rte(v - hf);
}

// ---------------------------------------------------------------------------
// step_mfma: r3-VERIFIED single-wave step kernel (body-t0 dual + fallback).
// ---------------------------------------------------------------------------
struct StepDir {
    const u16* Wih_h; const u16* Wih_l;
    const u16* Whh_h; const u16* Whh_l;
    const float* bih; const float* bhh;
    const u16* hh; const u16* hl;
    u16* oh; u16* ol;
    float* c;
    float* ex; long exs;
    int t;
};

__global__ __launch_bounds__(64) void step_mfma(
    const u16* __restrict__ xh, const u16* __restrict__ xl,
    StepDir d0, StepDir d1)
{
    StepDir D = blockIdx.z ? d1 : d0;
    const int gx   = blockIdx.x;
    const int xcd  = gx & 7, j = gx >> 3;
    const int cblk = xcd * 4 + (j & 3);
    const int rblk = j >> 2;
    const int lane = threadIdx.x;
    const int lr   = lane & 15;
    const int lk8  = (lane >> 4) * 8;
    const int b0   = rblk * 32;
    const int col  = cblk * 16 + lr;

    f32x4 acc[2][4];
    #pragma unroll
    for (int g = 0; g < 4; ++g) {
        float bs = D.bih[g * HD + col] + D.bhh[g * HD + col];
        acc[0][g] = f32x4{bs, bs, bs, bs};
        acc[1][g] = f32x4{bs, bs, bs, bs};
    }

    u16x8 Ah0[2], Al0[2], Bh0[4], Bl0[4];
    u16x8 Ah1[2], Al1[2], Bh1[4], Bl1[4];

    auto MMA = [&](u16x8 (&Ah)[2], u16x8 (&Al)[2], u16x8 (&Bh)[4], u16x8 (&Bl)[4]) {
        #pragma unroll
        for (int rt = 0; rt < 2; ++rt)
            #pragma unroll
            for (int g = 0; g < 4; ++g) {
                mfma16(acc[rt][g], Ah[rt], Bh[g]);
                mfma16(acc[rt][g], Ah[rt], Bl[g]);
                mfma16(acc[rt][g], Al[rt], Bh[g]);
            }
    };

    {
        auto LD = [&](u16x8 (&Ah)[2], u16x8 (&Al)[2], u16x8 (&Bh)[4], u16x8 (&Bl)[4], int ks) {
            const int ko = ks * 32 + lk8;
            #pragma unroll
            for (int rt = 0; rt < 2; ++rt) {
                long off = ((long)(b0 + rt * 16 + lr) * TDIM + D.t) * 320 + ko;
                Ah[rt] = *(const u16x8*)(xh + off);
                Al[rt] = *(const u16x8*)(xl + off);
            }
            #pragma unroll
            for (int g = 0; g < 4; ++g) {
                long off = (long)(g * HD + col) * 320 + ko;
                Bh[g] = *(const u16x8*)(D.Wih_h + off);
                Bl[g] = *(const u16x8*)(D.Wih_l + off);
            }
        };
        LD(Ah0, Al0, Bh0, Bl0, 0);
        #pragma unroll
        for (int ks = 0; ks < 10; ks += 2) {
            LD(Ah1, Al1, Bh1, Bl1, ks + 1);
            MMA(Ah0, Al0, Bh0, Bl0);
            if (ks + 2 < 10) LD(Ah0, Al0, Bh0, Bl0, ks + 2);
            MMA(Ah1, Al1, Bh1, Bl1);
        }
    }
    {
        auto LD = [&](u16x8 (&Ah)[2], u16x8 (&Al)[2], u16x8 (&Bh)[4], u16x8 (&Bl)[4], int ks) {
            const int ko = ks * 32 + lk8;
            #pragma unroll
            for (int rt = 0; rt < 2; ++rt) {
                long off = (long)(b0 + rt * 16 + lr) * HD + ko;
                Ah[rt] = *(const u16x8*)(D.hh + off);
                Al[rt] = *(const u16x8*)(D.hl + off);
            }
            #pragma unroll
            for (int g = 0; g < 4; ++g) {
                long off = (long)(g * HD + col) * HD + ko;
                Bh[g] = *(const u16x8*)(D.Whh_h + off);
                Bl[g] = *(const u16x8*)(D.Whh_l + off);
            }
        };
        LD(Ah0, Al0, Bh0, Bl0, 0);
        #pragma unroll
        for (int ks = 0; ks < 16; ks += 2) {
            LD(Ah1, Al1, Bh1, Bl1, ks + 1);
            MMA(Ah0, Al0, Bh0, Bl0);
            if (ks + 2 < 16) LD(Ah0, Al0, Bh0, Bl0, ks + 2);
            MMA(Ah1, Al1, Bh1, Bl1);
        }
    }

    #pragma unroll
    for (int rt = 0; rt < 2; ++rt) {
        #pragma unroll
        for (int r = 0; r < 4; ++r) {
            const int b = b0 + rt * 16 + (lane >> 4) * 4 + r;
            const long hoff = (long)b * HD + col;
            float iv = acc[rt][0][r];
            float fv = acc[rt][1][r];
            float gv = acc[rt][2][r];
            float ov = acc[rt][3][r];
            float cp = D.c[hoff];
            float si = 1.f / (1.f + expf(-iv));
            float sf = 1.f / (1.f + expf(-fv));
            float so = 1.f / (1.f + expf(-ov));
            float cn = sf * cp + si * tanhf(gv);
            float hn = so * tanhf(cn);
            D.c[hoff] = cn;
            u16 hb = bf16_rte(hn);
            D.oh[hoff] = hb;
            D.ol[hoff] = bf16_rte(hn - __builtin_bit_cast(float, (unsigned)hb << 16));
            if (D.ex) D.ex[(long)b * D.exs + col] = hn;
        }
    }
}

// ---------------------------------------------------------------------------
// xg_mfma: slab tloc = bias[col] + x[t0abs + tstep*tloc] @ Wih^T  (r6-verified)
// ---------------------------------------------------------------------------
__global__ __launch_bounds__(64) void xg_mfma(
    const u16* __restrict__ xh, const u16* __restrict__ xl,
    const u16* __restrict__ Wih_h, const u16* __restrict__ Wih_l,
    const float* __restrict__ bih, const float* __restrict__ bhh,
    float* __restrict__ xgT, int t0abs, int tstep)
{
    const int bx   = blockIdx.x;
    const int tloc = bx >> 9;
    const int rem  = bx & 511;
    const int rblk = rem >> 6;
    const int cgrp = rem & 63;
    const int lane = threadIdx.x;
    const int lr = lane & 15, lk8 = (lane >> 4) * 8;
    const int b0 = rblk * 32;
    const int tx = t0abs + tstep * tloc;
    const int colf0 = cgrp * 32 + lr;
    const int colf1 = colf0 + 16;

    f32x4 acc[2][2];
    {
        float bs0 = bih[colf0] + bhh[colf0];
        float bs1 = bih[colf1] + bhh[colf1];
        acc[0][0] = f32x4{bs0, bs0, bs0, bs0};
        acc[1][0] = f32x4{bs0, bs0, bs0, bs0};
        acc[0][1] = f32x4{bs1, bs1, bs1, bs1};
        acc[1][1] = f32x4{bs1, bs1, bs1, bs1};
    }

    u16x8 a0h[2], a0l[2], b0h[2], b0l[2];
    u16x8 a1h[2], a1l[2], b1h[2], b1l[2];

    auto LD = [&](u16x8 (&Ah)[2], u16x8 (&Al)[2], u16x8 (&Bh)[2], u16x8 (&Bl)[2], int ks) {
        const int ko = ks * 32 + lk8;
        #pragma unroll
        for (int rt = 0; rt < 2; ++rt) {
            long off = ((long)(b0 + rt * 16 + lr) * TDIM + tx) * 320 + ko;
            Ah[rt] = *(const u16x8*)(xh + off);
            Al[rt] = *(const u16x8*)(xl + off);
        }
        long w0 = (long)colf0 * 320 + ko;
        long w1 = (long)colf1 * 320 + ko;
        Bh[0] = *(const u16x8*)(Wih_h + w0);
        Bl[0] = *(const u16x8*)(Wih_l + w0);
        Bh[1] = *(const u16x8*)(Wih_h + w1);
        Bl[1] = *(const u16x8*)(Wih_l + w1);
    };
    auto MMA = [&](u16x8 (&Ah)[2], u16x8 (&Al)[2], u16x8 (&Bh)[2], u16x8 (&Bl)[2]) {
        #pragma unroll
        for (int rt = 0; rt < 2; ++rt)
            #pragma unroll
            for (int cf = 0; cf < 2; ++cf) {
                mfma16(acc[rt][cf], Ah[rt], Bh[cf]);
                mfma16(acc[rt][cf], Ah[rt], Bl[cf]);
                mfma16(acc[rt][cf], Al[rt], Bh[cf]);
            }
    };

    LD(a0h, a0l, b0h, b0l, 0);
    #pragma unroll
    for (int ks = 0; ks < 10; ks += 2) {
        LD(a1h, a1l, b1h, b1l, ks + 1);
        MMA(a0h, a0l, b0h, b0l);
        if (ks + 2 < 10) LD(a0h, a0l, b0h, b0l, ks + 2);
        MMA(a1h, a1l, b1h, b1l);
    }

    #pragma unroll
    for (int rt = 0; rt < 2; ++rt) {
        long o0 = ((long)tloc * 2048 + colf0) * 256 + b0 + rt * 16 + (lane >> 4) * 4;
        long o1 = ((long)tloc * 2048 + colf1) * 256 + b0 + rt * 16 + (lane >> 4) * 4;
        *(f32x4*)(xgT + o0) = acc[rt][0];
        *(f32x4*)(xgT + o1) = acc[rt][1];
    }
}

// ---------------------------------------------------------------------------
// Per-rblk-group grid barrier (32 blocks/group), r5..r9-verified.
// ---------------------------------------------------------------------------
__device__ __forceinline__ void group_bar(unsigned* cnt, unsigned* gen,
                                          unsigned nb, unsigned g)
{
    __syncthreads();
    if (threadIdx.x == 0) {
        unsigned old = __hip_atomic_fetch_add(cnt, 1u, __ATOMIC_RELEASE,
                                              __HIP_MEMORY_SCOPE_AGENT);
        if (old == nb - 1u) {
            __hip_atomic_store(cnt, 0u, __ATOMIC_RELAXED, __HIP_MEMORY_SCOPE_AGENT);
            __hip_atomic_store(gen, g + 1u, __ATOMIC_RELEASE, __HIP_MEMORY_SCOPE_AGENT);
        } else {
            while (__hip_atomic_load(gen, __ATOMIC_RELAXED, __HIP_MEMORY_SCOPE_AGENT) < g + 1u)
                __builtin_amdgcn_s_sleep(2);
            (void)__hip_atomic_load(gen, __ATOMIC_ACQUIRE, __HIP_MEMORY_SCOPE_AGENT);
        }
    }
    __syncthreads();
}

// ---------------------------------------------------------------------------
// lstm_persist: r9-VERIFIED (4.87ms config) — XCD-pinned groups, 4-wave
// K-split, per-step cst read/write, nontemporal xgT load. UNCHANGED.
// ---------------------------------------------------------------------------
__global__ __launch_bounds__(256) void lstm_persist(
    const float* __restrict__ xgT,
    const u16* __restrict__ Whh_h, const u16* __restrict__ Whh_l,
    u16* __restrict__ hAh, u16* __restrict__ hAl,
    u16* __restrict__ hBh, u16* __restrict__ hBl,
    float* __restrict__ cst,
    float* __restrict__ ex, long ex_bstride, int ex_t0, int ex_tstep,
    int ex_coff, int ex_final,
    unsigned* __restrict__ bars, int s0, int L)
{
    const int gx   = blockIdx.x;
    const int rblk = gx & 7;
    const int cblk = gx >> 3;
    const int wid  = threadIdx.x >> 6;
    const int lane = threadIdx.x & 63;
    const int lr   = lane & 15;
    const int lk8  = (lane >> 4) * 8;
    const int b0   = rblk * 32;
    const int col  = cblk * 16 + lr;

    __shared__ u16 WH[64][520];
    __shared__ u16 WL[64][520];
    __shared__ f32x4 RED[3][64][8];

    for (int idx = threadIdx.x; idx < 64 * 64; idx += 256) {
        int rr = idx >> 6;
        int kk = (idx & 63) << 3;
        int g = rr >> 4, cc = rr & 15;
        long gro = (long)(g * HD + cblk * 16 + cc) * HD + kk;
        *(u16x8*)&WH[rr][kk] = *(const u16x8*)(Whh_h + gro);
        *(u16x8*)&WL[rr][kk] = *(const u16x8*)(Whh_l + gro);
    }
    __syncthreads();

    unsigned* bcnt = bars + rblk * 64;
    unsigned* bgen = bars + 512 + rblk * 64;
    unsigned gen = 0;
    const int ksbase = wid * 4;

    for (int ti = 0; ti < L; ++ti) {
        const int s = s0 + ti;
        const u16* hih = (s & 1) ? hBh : hAh;
        const u16* hil = (s & 1) ? hBl : hAl;
        u16* hoh = (s & 1) ? hAh : hBh;
        u16* hol = (s & 1) ? hAl : hBl;

        f32x4 acc[2][4];
        if (wid == 0) {
            #pragma unroll
            for (int rt = 0; rt < 2; ++rt)
                #pragma unroll
                for (int g = 0; g < 4; ++g) {
                    long o = ((long)ti * 2048 + g * HD + col) * 256
                             + b0 + rt * 16 + (lane >> 4) * 4;
                    acc[rt][g] = __builtin_nontemporal_load((const f32x4*)(xgT + o));
                }
        } else {
            #pragma unroll
            for (int rt = 0; rt < 2; ++rt)
                #pragma unroll
                for (int g = 0; g < 4; ++g) acc[rt][g] = f32x4{0.f, 0.f, 0.f, 0.f};
        }

        u16x8 Ah0[2], Al0[2], Bh0[4], Bl0[4];
        u16x8 Ah1[2], Al1[2], Bh1[4], Bl1[4];

        auto MMA = [&](u16x8 (&Ah)[2], u16x8 (&Al)[2], u16x8 (&Bh)[4], u16x8 (&Bl)[4]) {
            #pragma unroll
            for (int rt = 0; rt < 2; ++rt)
                #pragma unroll
                for (int g = 0; g < 4; ++g) {
                    mfma16(acc[rt][g], Ah[rt], Bh[g]);
                    mfma16(acc[rt][g], Ah[rt], Bl[g]);
                    mfma16(acc[rt][g], Al[rt], Bh[g]);
                }
        };
        auto LD = [&](u16x8 (&Ah)[2], u16x8 (&Al)[2], u16x8 (&Bh)[4], u16x8 (&Bl)[4], int ks) {
            const int ko = ks * 32 + lk8;
            #pragma unroll
            for (int rt = 0; rt < 2; ++rt) {
                long off = (long)(b0 + rt * 16 + lr) * HD + ko;
                Ah[rt] = *(const u16x8*)(hih + off);
                Al[rt] = *(const u16x8*)(hil + off);
            }
            #pragma unroll
            for (int g = 0; g < 4; ++g) {
                Bh[g] = *(const u16x8*)&WH[g * 16 + lr][ko];
                Bl[g] = *(const u16x8*)&WL[g * 16 + lr][ko];
            }
        };

        LD(Ah0, Al0, Bh0, Bl0, ksbase + 0);
        LD(Ah1, Al1, Bh1, Bl1, ksbase + 1);
        MMA(Ah0, Al0, Bh0, Bl0);
        LD(Ah0, Al0, Bh0, Bl0, ksbase + 2);
        MMA(Ah1, Al1, Bh1, Bl1);
        LD(Ah1, Al1, Bh1, Bl1, ksbase + 3);
        MMA(Ah0, Al0, Bh0, Bl0);
        MMA(Ah1, Al1, Bh1, Bl1);

        if (wid != 0) {
            #pragma unroll
            for (int rt = 0; rt < 2; ++rt)
                #pragma unroll
                for (int g = 0; g < 4; ++g)
                    RED[wid - 1][lane][rt * 4 + g] = acc[rt][g];
        }
        __syncthreads();

        if (wid == 0) {
            #pragma unroll
            for (int w = 0; w < 3; ++w)
                #pragma unroll
                for (int rt = 0; rt < 2; ++rt)
                    #pragma unroll
                    for (int g = 0; g < 4; ++g)
                        acc[rt][g] += RED[w][lane][rt * 4 + g];

            const bool exw = (ex_final == -2) || (ex_final >= 0 && ti == ex_final);
            const int tt = ex_t0 + ex_tstep * ti;
            #pragma unroll
            for (int rt = 0; rt < 2; ++rt) {
                #pragma unroll
                for (int r = 0; r < 4; ++r) {
                    const int b = b0 + rt * 16 + (lane >> 4) * 4 + r;
                    const long hoff = (long)b * HD + col;
                    float iv = acc[rt][0][r];
                    float fv = acc[rt][1][r];
                    float gv = acc[rt][2][r];
                    float ov = acc[rt][3][r];
                    float cp = cst[hoff];
                    float si = 1.f / (1.f + expf(-iv));
                    float sf = 1.f / (1.f + expf(-fv));
                    float so = 1.f / (1.f + expf(-ov));
                    float cn = sf * cp + si * tanhf(gv);
                    float hn = so * tanhf(cn);
                    cst[hoff] = cn;
                    u16 hb = bf16_rte(hn);
                    hoh[hoff] = hb;
                    hol[hoff] = bf16_rte(hn - __builtin_bit_cast(float, (unsigned)hb << 16));
                    if (exw) ex[(long)b * ex_bstride + (long)tt * 1024 + ex_coff + col] = hn;
                }
            }
        }
        if (ti + 1 < L) { group_bar(bcnt, bgen, 32u, gen); ++gen; }
    }
}

// ---------------------------------------------------------------------------
// lstm_persist_dual (r12): BOTH title directions in ONE dispatch.
// 256 blocks = 8 XCD-pinned groups; groups 0-3 = dir0, 4-7 = dir1 (disjoint
// XCDs, independent barrier/h traffic). Each block covers 64 batch rows as
// TWO sequential 32-row tiles; per-tile MMA/reduce/epilogue is VERBATIM the
// r9 lstm_persist (RED reused between tiles with an extra __syncthreads).
// Numerics bit-identical to two r9 dispatches.
// ---------------------------------------------------------------------------
struct DualDir {
    const u16* Whh_h; const u16* Whh_l;
    u16 *hAh, *hAl, *hBh, *hBl;
    float* cst;
    float* ex; long exb; int ext0, extstep, excoff;
};

__global__ __launch_bounds__(256) void lstm_persist_dual(
    const float* __restrict__ xgT, long dirStride,
    DualDir d0, DualDir d1,
    unsigned* __restrict__ bars, int s0, int L)
{
    const int gx   = blockIdx.x;
    const int grp  = gx & 7;            // XCD-pinned group
    const int dir  = grp >> 2;          // 0..1
    const int rb2  = grp & 3;           // 64-row group within dir
    const int cblk = gx >> 3;           // 0..31 col tile
    const int wid  = threadIdx.x >> 6;
    const int lane = threadIdx.x & 63;
    const int lr   = lane & 15;
    const int lk8  = (lane >> 4) * 8;
    const int col  = cblk * 16 + lr;

    const DualDir D = dir ? d1 : d0;
    const float* xgD = xgT + (dir ? dirStride : 0);

    __shared__ u16 WH[64][520];
    __shared__ u16 WL[64][520];
    __shared__ f32x4 RED[3][64][8];

    for (int idx = threadIdx.x; idx < 64 * 64; idx += 256) {
        int rr = idx >> 6;
        int kk = (idx & 63) << 3;
        int g = rr >> 4, cc = rr & 15;
        long gro = (long)(g * HD + cblk * 16 + cc) * HD + kk;
        *(u16x8*)&WH[rr][kk] = *(const u16x8*)(D.Whh_h + gro);
        *(u16x8*)&WL[rr][kk] = *(const u16x8*)(D.Whh_l + gro);
    }
    __syncthreads();

    unsigned* bcnt = bars + grp * 64;
    unsigned* bgen = bars + 512 + grp * 64;
    unsigned gen = 0;
    const int ksbase = wid * 4;

    for (int ti = 0; ti < L; ++ti) {
        const int s = s0 + ti;
        const u16* hih = (s & 1) ? D.hBh : D.hAh;
        const u16* hil = (s & 1) ? D.hBl : D.hAl;
        u16* hoh = (s & 1) ? D.hAh : D.hBh;
        u16* hol = (s & 1) ? D.hAl : D.hBl;

        #pragma unroll
        for (int t2 = 0; t2 < 2; ++t2) {
            const int b0 = rb2 * 64 + t2 * 32;

            f32x4 acc[2][4];
            if (wid == 0) {
                #pragma unroll
                for (int rt = 0; rt < 2; ++rt)
                    #pragma unroll
                    for (int g = 0; g < 4; ++g) {
                        long o = ((long)ti * 2048 + g * HD + col) * 256
                                 + b0 + rt * 16 + (lane >> 4) * 4;
                        acc[rt][g] = __builtin_nontemporal_load((const f32x4*)(xgD + o));
                    }
            } else {
                #pragma unroll
                for (int rt = 0; rt < 2; ++rt)
                    #pragma unroll
                    for (int g = 0; g < 4; ++g) acc[rt][g] = f32x4{0.f, 0.f, 0.f, 0.f};
            }

            u16x8 Ah0[2], Al0[2], Bh0[4], Bl0[4];
            u16x8 Ah1[2], Al1[2], Bh1[4], Bl1[4];

            auto MMA = [&](u16x8 (&Ah)[2], u16x8 (&Al)[2], u16x8 (&Bh)[4], u16x8 (&Bl)[4]) {
                #pragma unroll
                for (int rt = 0; rt < 2; ++rt)
                    #pragma unroll
                    for (int g = 0; g < 4; ++g) {
                        mfma16(acc[rt][g], Ah[rt], Bh[g]);
                        mfma16(acc[rt][g], Ah[rt], Bl[g]);
                        mfma16(acc[rt][g], Al[rt], Bh[g]);
                    }
            };
            auto LD = [&](u16x8 (&Ah)[2], u16x8 (&Al)[2], u16x8 (&Bh)[4], u16x8 (&Bl)[4], int ks) {
                const int ko = ks * 32 + lk8;
                #pragma unroll
                for (int rt = 0; rt < 2; ++rt) {
                    long off = (long)(b0 + rt * 16 + lr) * HD + ko;
                    Ah[rt] = *(const u16x8*)(hih + off);
                    Al[rt] = *(const u16x8*)(hil + off);
                }
                #pragma unroll
                for (int g = 0; g < 4; ++g) {
                    Bh[g] = *(const u16x8*)&WH[g * 16 + lr][ko];
                    Bl[g] = *(const u16x8*)&WL[g * 16 + lr][ko];
                }
            };

            LD(Ah0, Al0, Bh0, Bl0, ksbase + 0);
            LD(Ah1, Al1, Bh1, Bl1, ksbase + 1);
            MMA(Ah0, Al0, Bh0, Bl0);
            LD(Ah0, Al0, Bh0, Bl0, ksbase + 2);
            MMA(Ah1, Al1, Bh1, Bl1);
            LD(Ah1, Al1, Bh1, Bl1, ksbase + 3);
            MMA(Ah0, Al0, Bh0, Bl0);
            MMA(Ah1, Al1, Bh1, Bl1);

            if (wid != 0) {
                #pragma unroll
                for (int rt = 0; rt < 2; ++rt)
                    #pragma unroll
                    for (int g = 0; g < 4; ++g)
                        RED[wid - 1][lane][rt * 4 + g] = acc[rt][g];
            }
            __syncthreads();

            if (wid == 0) {
                #pragma unroll
                for (int w = 0; w < 3; ++w)
                    #pragma unroll
                    for (int rt = 0; rt < 2; ++rt)
                        #pragma unroll
                        for (int g = 0; g < 4; ++g)
                            acc[rt][g] += RED[w][lane][rt * 4 + g];

                const int tt = D.ext0 + D.extstep * ti;
                #pragma unroll
                for (int rt = 0; rt < 2; ++rt) {
                    #pragma unroll
                    for (int r = 0; r < 4; ++r) {
                        const int b = b0 + rt * 16 + (lane >> 4) * 4 + r;
                        const long hoff = (long)b * HD + col;
                        float iv = acc[rt][0][r];
                        float fv = acc[rt][1][r];
                        float gv = acc[rt][2][r];
                        float ov = acc[rt][3][r];
                        float cp = D.cst[hoff];
                        float si = 1.f / (1.f + expf(-iv));
                        float sf = 1.f / (1.f + expf(-fv));
                        float so = 1.f / (1.f + expf(-ov));
                        float cn = sf * cp + si * tanhf(gv);
                        float hn = so * tanhf(cn);
                        D.cst[hoff] = cn;
                        u16 hb = bf16_rte(hn);
                        hoh[hoff] = hb;
                        hol[hoff] = bf16_rte(hn - __builtin_bit_cast(float, (unsigned)hb << 16));
                        D.ex[(long)b * D.exb + (long)tt * 1024 + D.excoff + col] = hn;
                    }
                }
            }
            __syncthreads();   // RED safe to reuse / all writes visible in-block
        }
        if (ti + 1 < L) { group_bar(bcnt, bgen, 32u, gen); ++gen; }
    }
}

// ---------------------------------------------------------------------------
// body_persist: r5-verified 1-wave fallback (inline phase 1), small-ws path.
// ---------------------------------------------------------------------------
__global__ __launch_bounds__(64) void body_persist(
    const u16* __restrict__ xh, const u16* __restrict__ xl,
    const u16* __restrict__ Wih_h, const u16* __restrict__ Wih_l,
    const u16* __restrict__ Whh_h, const u16* __restrict__ Whh_l,
    const float* __restrict__ bih, const float* __restrict__ bhh,
    u16* __restrict__ hAh, u16* __restrict__ hAl,
    u16* __restrict__ hBh, u16* __restrict__ hBl,
    float* __restrict__ cst, float* __restrict__ ex,
    unsigned* __restrict__ bars)
{
    const int gx   = blockIdx.x;
    const int xcd  = gx & 7, j = gx >> 3;
    const int cblk = xcd * 4 + (j & 3);
    const int rblk = j >> 2;
    const int lane = threadIdx.x;
    const int lr   = lane & 15;
    const int lk8  = (lane >> 4) * 8;
    const int b0   = rblk * 32;
    const int col  = cblk * 16 + lr;

    __shared__ u16 WH[64][520];
    __shared__ u16 WL[64][520];
    for (int idx = lane; idx < 64 * 64; idx += 64) {
        int rr = idx >> 6;
        int kk = (idx & 63) << 3;
        int g = rr >> 4, cc = rr & 15;
        long gro = (long)(g * HD + cblk * 16 + cc) * HD + kk;
        *(u16x8*)&WH[rr][kk] = *(const u16x8*)(Whh_h + gro);
        *(u16x8*)&WL[rr][kk] = *(const u16x8*)(Whh_l + gro);
    }
    __syncthreads();

    float bsum[4];
    #pragma unroll
    for (int g = 0; g < 4; ++g) bsum[g] = bih[g * HD + col] + bhh[g * HD + col];

    unsigned* bcnt = bars + rblk * 64;
    unsigned* bgen = bars + 512 + rblk * 64;
    unsigned gen = 0;

    for (int t = 1; t < 200; ++t) {
        const int s = 40 + t;
        const u16* hih = (s & 1) ? hBh : hAh;
        const u16* hil = (s & 1) ? hBl : hAl;
        u16* hoh = (s & 1) ? hAh : hBh;
        u16* hol = (s & 1) ? hAl : hBl;

        f32x4 acc[2][4];
        #pragma unroll
        for (int g = 0; g < 4; ++g) {
            acc[0][g] = f32x4{bsum[g], bsum[g], bsum[g], bsum[g]};
            acc[1][g] = f32x4{bsum[g], bsum[g], bsum[g], bsum[g]};
        }

        u16x8 Ah0[2], Al0[2], Bh0[4], Bl0[4];
        u16x8 Ah1[2], Al1[2], Bh1[4], Bl1[4];

        auto MMA = [&](u16x8 (&Ah)[2], u16x8 (&Al)[2], u16x8 (&Bh)[4], u16x8 (&Bl)[4]) {
            #pragma unroll
            for (int rt = 0; rt < 2; ++rt)
                #pragma unroll
                for (int g = 0; g < 4; ++g) {
                    mfma16(acc[rt][g], Ah[rt], Bh[g]);
                    mfma16(acc[rt][g], Ah[rt], Bl[g]);
                    mfma16(acc[rt][g], Al[rt], Bh[g]);
                }
        };
        {
            auto LD = [&](u16x8 (&Ah)[2], u16x8 (&Al)[2], u16x8 (&Bh)[4], u16x8 (&Bl)[4], int ks) {
                const int ko = ks * 32 + lk8;
                #pragma unroll
                for (int rt = 0; rt < 2; ++rt) {
                    long off = ((long)(b0 + rt * 16 + lr) * TDIM + (40 + t)) * 320 + ko;
                    Ah[rt] = *(const u16x8*)(xh + off);
                    Al[rt] = *(const u16x8*)(xl + off);
                }
                #pragma unroll
                for (int g = 0; g < 4; ++g) {
                    long off = (long)(g * HD + col) * 320 + ko;
                    Bh[g] = *(const u16x8*)(Wih_h + off);
                    Bl[g] = *(const u16x8*)(Wih_l + off);
                }
            };
            LD(Ah0, Al0, Bh0, Bl0, 0);
            #pragma unroll
            for (int ks = 0; ks < 10; ks += 2) {
                LD(Ah1, Al1, Bh1, Bl1, ks + 1);
                MMA(Ah0, Al0, Bh0, Bl0);
                if (ks + 2 < 10) LD(Ah0, Al0, Bh0, Bl0, ks + 2);
                MMA(Ah1, Al1, Bh1, Bl1);
            }
        }
        {
            auto LD = [&](u16x8 (&Ah)[2], u16x8 (&Al)[2], u16x8 (&Bh)[4], u16x8 (&Bl)[4], int ks) {
                const int ko = ks * 32 + lk8;
                #pragma unroll
                for (int rt = 0; rt < 2; ++rt) {
                    long off = (long)(b0 + rt * 16 + lr) * HD + ko;
                    Ah[rt] = *(const u16x8*)(hih + off);
                    Al[rt] = *(const u16x8*)(hil + off);
                }
                #pragma unroll
                for (int g = 0; g < 4; ++g) {
                    Bh[g] = *(const u16x8*)&WH[g * 16 + lr][ko];
                    Bl[g] = *(const u16x8*)&WL[g * 16 + lr][ko];
                }
            };
            LD(Ah0, Al0, Bh0, Bl0, 0);
            #pragma unroll
            for (int ks = 0; ks < 16; ks += 2) {
                LD(Ah1, Al1, Bh1, Bl1, ks + 1);
                MMA(Ah0, Al0, Bh0, Bl0);
                if (ks + 2 < 16) LD(Ah0, Al0, Bh0, Bl0, ks + 2);
                MMA(Ah1, Al1, Bh1, Bl1);
            }
        }
        float* exw = (t == 199) ? ex : (float*)nullptr;
        #pragma unroll
        for (int rt = 0; rt < 2; ++rt) {
            #pragma unroll
            for (int r = 0; r < 4; ++r) {
                const int b = b0 + rt * 16 + (lane >> 4) * 4 + r;
                const long hoff = (long)b * HD + col;
                float iv = acc[rt][0][r];
                float fv = acc[rt][1][r];
                float gv = acc[rt][2][r];
                float ov = acc[rt][3][r];
                float cp = cst[hoff];
                float si = 1.f / (1.f + expf(-iv));
                float sf = 1.f / (1.f + expf(-fv));
                float so = 1.f / (1.f + expf(-ov));
                float cn = sf * cp + si * tanhf(gv);
                float hn = so * tanhf(cn);
                cst[hoff] = cn;
                u16 hb = bf16_rte(hn);
                hoh[hoff] = hb;
                hol[hoff] = bf16_rte(hn - __builtin_bit_cast(float, (unsigned)hb << 16));
                if (exw) exw[(long)b * 1024 + col] = hn;
            }
        }
        group_bar(bcnt, bgen, 32u, gen);
        ++gen;
    }
}

// ---------------------------------------------------------------------------
// Generic bf16-split MFMA GEMM (epilogue): r3-verified.
// ---------------------------------------------------------------------------
template<int ACT>
__global__ __launch_bounds__(64) void mfma_gemm(
    const u16* __restrict__ Ah_, const u16* __restrict__ Al_,
    const u16* __restrict__ Wh_, const u16* __restrict__ Wl_,
    const float* __restrict__ bias, float* __restrict__ C,
    int ldc, int K, int n16)
{
    const int gx = blockIdx.x;
    const int nblk = gx % n16, mblk = gx / n16;
    const int lane = threadIdx.x;
    const int lr = lane & 15, lk8 = (lane >> 4) * 8;
    const int b0 = mblk * 32, col = nblk * 16 + lr;

    f32x4 acc[2] = {f32x4{0,0,0,0}, f32x4{0,0,0,0}};
    u16x8 A0[2], L0[2], A1[2], L1[2];
    u16x8 B0, M0, B1, M1;

    auto LD = [&](u16x8 (&A)[2], u16x8 (&L)[2], u16x8& B, u16x8& M, int ks) {
        const int ko = ks * 32 + lk8;
        #pragma unroll
        for (int rt = 0; rt < 2; ++rt) {
            long off = (long)(b0 + rt * 16 + lr) * K + ko;
            A[rt] = *(const u16x8*)(Ah_ + off);
            L[rt] = *(const u16x8*)(Al_ + off);
        }
        long woff = (long)col * K + ko;
        B = *(const u16x8*)(Wh_ + woff);
        M = *(const u16x8*)(Wl_ + woff);
    };
    auto MMA = [&](u16x8 (&A)[2], u16x8 (&L)[2], u16x8& B, u16x8& M) {
        #pragma unroll
        for (int rt = 0; rt < 2; ++rt) {
            mfma16(acc[rt], A[rt], B);
            mfma16(acc[rt], A[rt], M);
            mfma16(acc[rt], L[rt], B);
        }
    };

    const int NS = K >> 5;
    LD(A0, L0, B0, M0, 0);
    for (int ks = 0; ks < NS; ks += 2) {
        if (ks + 1 < NS) LD(A1, L1, B1, M1, ks + 1);
        MMA(A0, L0, B0, M0);
        if (ks + 2 < NS) LD(A0, L0, B0, M0, ks + 2);
        if (ks + 1 < NS) MMA(A1, L1, B1, M1);
    }

    float bs = bias ? bias[col] : 0.f;
    #pragma unroll
    for (int rt = 0; rt < 2; ++rt)
        #pragma unroll
        for (int r = 0; r < 4; ++r) {
            int m = b0 + rt * 16 + (lane >> 4) * 4 + r;
            float v = acc[rt][r] + bs;
            if (ACT == 1) v = tanhf(v);
            C[(long)m * ldc + col] = v;
        }
}

// ---------------------------------------------------------------------------
// Legacy fp32 path (tiny workspace fallback) — r1-verified.
// ---------------------------------------------------------------------------
template<int BB>
__global__ __launch_bounds__(256) void lstm_step(
    const float* __restrict__ x,
    const float* __restrict__ Wih0, const float* __restrict__ Whh0,
    const float* __restrict__ bih0, const float* __restrict__ bhh0,
    const float* __restrict__ hin0, float* __restrict__ hnew0, float* __restrict__ cst0,
    float* __restrict__ ex0, int exs0, int tx0,
    const float* __restrict__ Wih1, const float* __restrict__ Whh1,
    const float* __restrict__ bih1, const float* __restrict__ bhh1,
    const float* __restrict__ hin1, float* __restrict__ hnew1, float* __restrict__ cst1,
    float* __restrict__ ex1, int exs1, int tx1)
{
    const int dir = blockIdx.z;
    const float* Wih = dir ? Wih1 : Wih0;
    const float* Whh = dir ? Whh1 : Whh0;
    const float* bih = dir ? bih1 : bih0;
    const float* bhh = dir ? bhh1 : bhh0;
    const float* hin = dir ? hin1 : hin0;
    float* hnew = dir ? hnew1 : hnew0;
    float* cst  = dir ? cst1  : cst0;
    float* ex   = dir ? ex1   : ex0;
    const int exs = dir ? exs1 : exs0;
    const int tx  = dir ? tx1  : tx0;

    const int bblk = blockIdx.x, kblk = blockIdx.y;
    const int tid = threadIdx.x;
    const int j  = tid & 15;
    const int ty = tid >> 4;
    const int k  = kblk * 16 + j;
    constexpr int RB = BB / 16;

    __shared__ float As[BB][33];
    __shared__ float Bs[32][65];

    float acc[RB][4];
    #pragma unroll
    for (int r = 0; r < RB; ++r)
        #pragma unroll
        for (int q = 0; q < 4; ++q) acc[r][q] = 0.f;

    const int lb = tid >> 5, lk = tid & 31;

    for (int kb = 0; kb < INDIM; kb += 32) {
        #pragma unroll
        for (int it = 0; it < BB/8; ++it) {
            int b = lb + it*8;
            int i = kb + lk;
            As[b][lk] = (i < INDIM) ? x[((bblk*BB + b)*TDIM + tx)*INDIM + i] : 0.f;
        }
        #pragma unroll
        for (int it = 0; it < 8; ++it) {
            int col = lb + it*8;
            int g = (col >> 4)*HD + kblk*16 + (col & 15);
            int i = kb + lk;
            Bs[lk][col] = (i < INDIM) ? Wih[g*INDIM + i] : 0.f;
        }
        __syncthreads();
        #pragma unroll
        for (int kk = 0; kk < 32; ++kk) {
            float a_[RB], b_[4];
            #pragma unroll
            for (int r = 0; r < RB; ++r) a_[r] = As[ty*RB + r][kk];
            #pragma unroll
            for (int q = 0; q < 4; ++q) b_[q] = Bs[kk][q*16 + j];
            #pragma unroll
            for (int r = 0; r < RB; ++r)
                #pragma unroll
                for (int q = 0; q < 4; ++q) acc[r][q] += a_[r]*b_[q];
        }
        __syncthreads();
    }
    for (int kb = 0; kb < HD; kb += 32) {
        #pragma unroll
        for (int it = 0; it < BB/8; ++it) {
            int b = lb + it*8;
            As[b][lk] = hin[(bblk*BB + b)*HD + kb + lk];
        }
        #pragma unroll
        for (int it = 0; it < 8; ++it) {
            int col = lb + it*8;
            int g = (col >> 4)*HD + kblk*16 + (col & 15);
            Bs[lk][col] = Whh[g*HD + kb + lk];
        }
        __syncthreads();
        #pragma unroll
        for (int kk = 0; kk < 32; ++kk) {
            float a_[RB], b_[4];
            #pragma unroll
            for (int r = 0; r < RB; ++r) a_[r] = As[ty*RB + r][kk];
            #pragma unroll
            for (int q = 0; q < 4; ++q) b_[q] = Bs[kk][q*16 + j];
            #pragma unroll
            for (int r = 0; r < RB; ++r)
                #pragma unroll
                for (int q = 0; q < 4; ++q) acc[r][q] += a_[r]*b_[q];
        }
        __syncthreads();
    }
    float bsum[4];
    #pragma unroll
    for (int q = 0; q < 4; ++q) bsum[q] = bih[q*HD + k] + bhh[q*HD + k];
    #pragma unroll
    for (int r = 0; r < RB; ++r) {
        int gb = bblk*BB + ty*RB + r;
        float iv = acc[r][0] + bsum[0];
        float fv = acc[r][1] + bsum[1];
        float gv = acc[r][2] + bsum[2];
        float ov = acc[r][3] + bsum[3];
        float cprev = cst[gb*HD + k];
        float si = 1.f/(1.f + expf(-iv));
        float sf = 1.f/(1.f + expf(-fv));
        float so = 1.f/(1.f + expf(-ov));
        float cn = sf*cprev + si*tanhf(gv);
        float hn = so*tanhf(cn);
        cst[gb*HD + k]  = cn;
        hnew[gb*HD + k] = hn;
        if (ex) ex[gb*exs + k] = hn;
    }
}

template<int ACT>
__global__ __launch_bounds__(256) void gemm_bias_act(
    const float* __restrict__ A, int lda,
    const float* __restrict__ W,
    const float* __restrict__ bias,
    float* __restrict__ C, int ldc,
    int K)
{
    const int mblk = blockIdx.x, nblk = blockIdx.y;
    const int tid = threadIdx.x;
    const int txd = tid & 15, ty = tid >> 4;
    __shared__ float As[32][33];
    __shared__ float Bs[32][65];
    float acc[2][4] = {{0.f,0.f,0.f,0.f},{0.f,0.f,0.f,0.f}};
    const int lb = tid >> 5, lk = tid & 31;

    for (int kb = 0; kb < K; kb += 32) {
        #pragma unroll
        for (int it = 0; it < 4; ++it) {
            int r = lb + it*8;
            As[r][lk] = A[(mblk*32 + r)*lda + kb + lk];
        }
        #pragma unroll
        for (int it = 0; it < 8; ++it) {
            int col = lb + it*8;
            Bs[lk][col] = W[(nblk*64 + col)*K + kb + lk];
        }
        __syncthreads();
        #pragma unroll
        for (int kk = 0; kk < 32; ++kk) {
            float a0 = As[ty*2 + 0][kk], a1 = As[ty*2 + 1][kk];
            float b_[4];
            #pragma unroll
            for (int q = 0; q < 4; ++q) b_[q] = Bs[kk][q*16 + txd];
            #pragma unroll
            for (int q = 0; q < 4; ++q) { acc[0][q] += a0*b_[q]; acc[1][q] += a1*b_[q]; }
        }
        __syncthreads();
    }
    #pragma unroll
    for (int r = 0; r < 2; ++r) {
        int m = mblk*32 + ty*2 + r;
        #pragma unroll
        for (int q = 0; q < 4; ++q) {
            int n = nblk*64 + q*16 + txd;
            float v = acc[r][q] + (bias ? bias[n] : 0.f);
            if (ACT == 1) v = tanhf(v);
            C[m*ldc + n] = v;
        }
    }
}

// ---------------------------------------------------------------------------
// attention softmax/context + small epilogue kernels
// ---------------------------------------------------------------------------
__global__ __launch_bounds__(256) void attn_ctx(
    const float* __restrict__ title_out,
    const float* __restrict__ u,
    const float* __restrict__ bilb,
    float* __restrict__ attn_in)
{
    int b = blockIdx.x;
    int tid = threadIdx.x;
    __shared__ float uL[1024];
    __shared__ float sc[40];
    for (int e = tid; e < 1024; e += 256) uL[e] = u[b*1024 + e];
    __syncthreads();
    int wave = tid >> 6, lane = tid & 63;
    for (int t = wave*10; t < wave*10 + 10; ++t) {
        const float* row = title_out + (b*40 + t)*1024;
        float s = 0.f;
        for (int e = lane; e < 1024; e += 64) s += row[e]*uL[e];
        #pragma unroll
        for (int off = 32; off > 0; off >>= 1) s += __shfl_down(s, off, 64);
        if (lane == 0) sc[t] = s + bilb[0];
    }
    __syncthreads();
    if (tid < 64) {
        float v = (tid < 40) ? sc[tid] : -1e30f;
        float m = v;
        #pragma unroll
        for (int off = 32; off > 0; off >>= 1) m = fmaxf(m, __shfl_xor(m, off, 64));
        float e = (tid < 40) ? expf(v - m) : 0.f;
        float ssum = e;
        #pragma unroll
        for (int off = 32; off > 0; off >>= 1) ssum += __shfl_xor(ssum, off, 64);
        if (tid < 40) sc[tid] = e / ssum;
    }
    __syncthreads();
    for (int e = tid; e < 1024; e += 256) {
        float a = 0.f;
        #pragma unroll
        for (int t = 0; t < 40; ++t) a += sc[t]*title_out[(b*40 + t)*1024 + e];
        attn_in[b*2048 + e] = a;
    }
}

__global__ void copy_rows(const float* __restrict__ src, int ss,
                          float* __restrict__ dst, int ds, int n)
{
    int b = blockIdx.x;
    for (int e = threadIdx.x; e < n; e += blockDim.x) dst[b*ds + e] = src[b*ss + e];
}

__global__ __launch_bounds__(64) void final_cls(
    const float* __restrict__ ch,
    const float* __restrict__ clsW,
    const float* __restrict__ clsb,
    float* __restrict__ out)
{
    int b = blockIdx.x*64 + threadIdx.x;
    float o[4];
    #pragma unroll
    for (int n = 0; n < 4; ++n) {
        float s = clsb[n];
        for (int jj = 0; jj < 512; ++jj) s += ch[b*512 + jj]*clsW[n*512 + jj];
        o[n] = s;
    }
    float m = fmaxf(fmaxf(o[0], o[1]), fmaxf(o[2], o[3]));
    float e0 = expf(o[0]-m), e1 = expf(o[1]-m), e2 = expf(o[2]-m), e3 = expf(o[3]-m);
    float s = e0 + e1 + e2 + e3;
    out[b*4+0] = e0/s; out[b*4+1] = e1/s; out[b*4+2] = e2/s; out[b*4+3] = e3/s;
}

// ---------------------------------------------------------------------------
extern "C" void kernel_launch(void* const* d_in, const int* in_sizes, int n_in,
                              void* d_out, int out_size, void* d_ws, size_t ws_size,
                              hipStream_t stream) {
    const float* x     = (const float*)d_in[0];
    const float* tWih  = (const float*)d_in[1];
    const float* tWhh  = (const float*)d_in[2];
    const float* tbih  = (const float*)d_in[3];
    const float* tbhh  = (const float*)d_in[4];
    const float* bWih  = (const float*)d_in[5];
    const float* bWhh  = (const float*)d_in[6];
    const float* bbih  = (const float*)d_in[7];
    const float* bbhh  = (const float*)d_in[8];
    const float* bilW  = (const float*)d_in[9];
    const float* bilb  = (const float*)d_in[10];
    const float* attnW = (const float*)d_in[11];
    const float* attnb = (const float*)d_in[12];
    const float* decW  = (const float*)d_in[13];
    const float* decb  = (const float*)d_in[14];
    const float* clsW  = (const float*)d_in[15];
    const float* clsb  = (const float*)d_in[16];

    char* base = (char*)d_ws;
    size_t off = 0;
    auto carve = [&](size_t bytes) -> void* {
        void* r = base + off; off += (bytes + 255) & ~(size_t)255; return r;
    };

    u16* hA0h = (u16*)carve(BATCH*HD*2);
    u16* hA0l = (u16*)carve(BATCH*HD*2);
    u16* hA1h = (u16*)carve(BATCH*HD*2);
    u16* hA1l = (u16*)carve(BATCH*HD*2);
    float* c0 = (float*)carve(BATCH*HD*4);
    float* c1 = (float*)carve(BATCH*HD*4);
    unsigned* bars = (unsigned*)carve(32*4096);
    size_t zero_bytes = off;
    u16* hB0h = (u16*)carve(BATCH*HD*2);
    u16* hB0l = (u16*)carve(BATCH*HD*2);
    u16* hB1h = (u16*)carve(BATCH*HD*2);
    u16* hB1l = (u16*)carve(BATCH*HD*2);
    u16* xh = (u16*)carve((size_t)BATCH*TDIM*320*2);
    u16* xl = (u16*)carve((size_t)BATCH*TDIM*320*2);
    u16* tW0ih_h = (u16*)carve(2048*320*2); u16* tW0ih_l = (u16*)carve(2048*320*2);
    u16* tW1ih_h = (u16*)carve(2048*320*2); u16* tW1ih_l = (u16*)carve(2048*320*2);
    u16* bW0ih_h = (u16*)carve(2048*320*2); u16* bW0ih_l = (u16*)carve(2048*320*2);
    u16* bW1ih_h = (u16*)carve(2048*320*2); u16* bW1ih_l = (u16*)carve(2048*320*2);
    u16* tW0hh_h = (u16*)carve(2048*512*2); u16* tW0hh_l = (u16*)carve(2048*512*2);
    u16* tW1hh_h = (u16*)carve(2048*512*2); u16* tW1hh_l = (u16*)carve(2048*512*2);
    u16* bW0hh_h = (u16*)carve(2048*512*2); u16* bW0hh_l = (u16*)carve(2048*512*2);
    u16* bW1hh_h = (u16*)carve(2048*512*2); u16* bW1hh_l = (u16*)carve(2048*512*2);
    float* title_out = (float*)carve((size_t)BATCH*40*1024*4);
    float* body_last = (float*)carve((size_t)BATCH*1024*4);
    float* u_buf     = (float*)carve((size_t)BATCH*1024*4);
    float* attn_in   = (float*)carve((size_t)BATCH*2048*4);
    float* out_cat   = (float*)carve((size_t)BATCH*2048*4);
    float* ch        = (float*)carve((size_t)BATCH*512*4);
    u16* bl_h = (u16*)carve((size_t)BATCH*1024*2); u16* bl_l = (u16*)carve((size_t)BATCH*1024*2);
    u16* ai_h = (u16*)carve((size_t)BATCH*2048*2); u16* ai_l = (u16*)carve((size_t)BATCH*2048*2);
    u16* oc_h = (u16*)carve((size_t)BATCH*2048*2); u16* oc_l = (u16*)carve((size_t)BATCH*2048*2);
    u16* bilW_h  = (u16*)carve(1024*1024*2); u16* bilW_l  = (u16*)carve(1024*1024*2);
    u16* attnW_h = (u16*)carve((size_t)1024*2048*2); u16* attnW_l = (u16*)carve((size_t)1024*2048*2);
    u16* decW_h  = (u16*)carve((size_t)512*2048*2);  u16* decW_l  = (u16*)carve((size_t)512*2048*2);
    size_t need = off;

    const size_t SLAB_BYTES = (size_t)2048 * 256 * 4;
    const long   SLABF = 2048L * 256;
    float* xgT = (float*)(base + off);
    size_t nslab = 0;
    if (ws_size > need) nslab = (ws_size - need) / SLAB_BYTES;
    int C = (int)(nslab > 50 ? 50 : nslab);            // body chunk size (r9)
    const bool xg_ok = (C >= 10);
    int C2 = (int)(nslab / 2 > 40 ? 40 : nslab / 2);   // merged title chunk
    const bool dual_ok = (C2 >= 10);

    if (ws_size >= need) {
        hipMemsetAsync(d_ws, 0, zero_bytes, stream);

        // ---- fused splits: one launch for x + all weights ----
        {
            SParams P;
            auto J = [&](int i, const float* s, u16* h, u16* l, long rows, int kin, int kout) {
                P.j[i] = { s, h, l, kin, kout };
                P.cum[i + 1] = P.cum[i] + rows * (long)kout;
            };
            P.cum[0] = 0;
            J(0,  x,                  xh,      xl,      (long)BATCH*TDIM, INDIM, 320);
            J(1,  tWih,               tW0ih_h, tW0ih_l, 2048, INDIM, 320);
            J(2,  tWih + 2048*INDIM,  tW1ih_h, tW1ih_l, 2048, INDIM, 320);
            J(3,  bWih,               bW0ih_h, bW0ih_l, 2048, INDIM, 320);
            J(4,  bWih + 2048*INDIM,  bW1ih_h, bW1ih_l, 2048, INDIM, 320);
            J(5,  tWhh,               tW0hh_h, tW0hh_l, 2048, HD, HD);
            J(6,  tWhh + 2048*HD,     tW1hh_h, tW1hh_l, 2048, HD, HD);
            J(7,  bWhh,               bW0hh_h, bW0hh_l, 2048, HD, HD);
            J(8,  bWhh + 2048*HD,     bW1hh_h, bW1hh_l, 2048, HD, HD);
            J(9,  bilW,               bilW_h,  bilW_l,  1024, 1024, 1024);
            J(10, attnW,              attnW_h, attnW_l, 1024, 2048, 2048);
            J(11, decW,               decW_h,  decW_l,  512,  2048, 2048);
            long total = P.cum[12];
            split_all<<<dim3((unsigned)((total + 255) / 256)), 256, 0, stream>>>(P);
        }

        if (xg_ok) {
            int ci = 0;
            // ---- title: both dirs merged per chunk (dual persist) ----
            if (dual_ok) {
                for (int tb = 0; tb < 40; tb += C2, ++ci) {
                    int L = (C2 < 40 - tb) ? C2 : (40 - tb);
                    xg_mfma<<<dim3((unsigned)(L*512)), 64, 0, stream>>>(
                        xh, xl, tW0ih_h, tW0ih_l, tbih, tbhh, xgT, tb, 1);
                    xg_mfma<<<dim3((unsigned)(L*512)), 64, 0, stream>>>(
                        xh, xl, tW1ih_h, tW1ih_l, tbih + 2048, tbhh + 2048,
                        xgT + (long)L * SLABF, 39 - tb, -1);
                    DualDir D0 = { tW0hh_h, tW0hh_l, hA0h, hA0l, hB0h, hB0l, c0,
                                   title_out, 40*1024, tb, 1, 0 };
                    DualDir D1 = { tW1hh_h, tW1hh_l, hA1h, hA1l, hB1h, hB1l, c1,
                                   title_out, 40*1024, 39 - tb, -1, 512 };
                    lstm_persist_dual<<<dim3(256), 256, 0, stream>>>(
                        xgT, (long)L * SLABF, D0, D1,
                        bars + (size_t)ci*1024, tb, L);
                }
            } else {
                for (int tb = 0; tb < 40; tb += C, ++ci) {
                    int L = (C < 40 - tb) ? C : (40 - tb);
                    xg_mfma<<<dim3((unsigned)(L*512)), 64, 0, stream>>>(
                        xh, xl, tW0ih_h, tW0ih_l, tbih, tbhh, xgT, tb, 1);
                    lstm_persist<<<dim3(256), 256, 0, stream>>>(
                        xgT, tW0hh_h, tW0hh_l, hA0h, hA0l, hB0h, hB0l, c0,
                        title_out, 40*1024, tb, 1, 0, -2,
                        bars + (size_t)ci*1024, tb, L);
                }
                for (int tb = 0; tb < 40; tb += C, ++ci) {
                    int L = (C < 40 - tb) ? C : (40 - tb);
                    xg_mfma<<<dim3((unsigned)(L*512)), 64, 0, stream>>>(
                        xh, xl, tW1ih_h, tW1ih_l, tbih + 2048, tbhh + 2048, xgT, 39 - tb, -1);
                    lstm_persist<<<dim3(256), 256, 0, stream>>>(
                        xgT, tW1hh_h, tW1hh_l, hA1h, hA1l, hB1h, hB1l, c1,
                        title_out, 40*1024, 39 - tb, -1, 512, -2,
                        bars + (size_t)ci*1024, tb, L);
                }
            }
            // ---- body t=0: fwd + single bwd step (tx=239) ----
            {
                StepDir F = { bW0ih_h, bW0ih_l, bW0hh_h, bW0hh_l, bbih, bbhh,
                              hA0h, hA0l, hB0h, hB0l, c0, (float*)nullptr, 0, 40 };
                StepDir R = { bW1ih_h, bW1ih_l, bW1hh_h, bW1hh_l, bbih + 2048, bbhh + 2048,
                              hA1h, hA1l, hB1h, hB1l, c1, body_last + 512, 1024, 239 };
                step_mfma<<<dim3(256,1,2), 64, 0, stream>>>(xh, xl, F, R);
            }
            // ---- body t=1..199: chunked persist (r9-verified) ----
            for (int tb = 1; tb < 200; tb += C, ++ci) {
                int L = (C < 200 - tb) ? C : (200 - tb);
                bool last = (tb + L == 200);
                xg_mfma<<<dim3((unsigned)(L*512)), 64, 0, stream>>>(
                    xh, xl, bW0ih_h, bW0ih_l, bbih, bbhh, xgT, 40 + tb, 1);
                lstm_persist<<<dim3(256), 256, 0, stream>>>(
                    xgT, bW0hh_h, bW0hh_l, hA0h, hA0l, hB0h, hB0l, c0,
                    body_last, 1024, 0, 0, 0, last ? (L - 1) : -1,
                    bars + (size_t)ci*1024, 40 + tb, L);
            }
        } else {
            // ---- fallback: r3/r5-verified step loop + 1-wave body persist ----
            for (int t = 0; t < 40; ++t) {
                bool odd = t & 1;
                StepDir A = { tW0ih_h, tW0ih_l, tW0hh_h, tW0hh_l, tbih, tbhh,
                              odd?hB0h:hA0h, odd?hB0l:hA0l, odd?hA0h:hB0h, odd?hA0l:hB0l,
                              c0, title_out + (size_t)t*1024, 40*1024, t };
                StepDir B = { tW1ih_h, tW1ih_l, tW1hh_h, tW1hh_l, tbih + 2048, tbhh + 2048,
                              odd?hB1h:hA1h, odd?hB1l:hA1l, odd?hA1h:hB1h, odd?hA1l:hB1l,
                              c1, title_out + (size_t)(39 - t)*1024 + 512, 40*1024, 39 - t };
                step_mfma<<<dim3(256,1,2), 64, 0, stream>>>(xh, xl, A, B);
            }
            {
                StepDir F = { bW0ih_h, bW0ih_l, bW0hh_h, bW0hh_l, bbih, bbhh,
                              hA0h, hA0l, hB0h, hB0l, c0, (float*)nullptr, 0, 40 };
                StepDir R = { bW1ih_h, bW1ih_l, bW1hh_h, bW1hh_l, bbih + 2048, bbhh + 2048,
                              hA1h, hA1l, hB1h, hB1l, c1, body_last + 512, 1024, 239 };
                step_mfma<<<dim3(256,1,2), 64, 0, stream>>>(xh, xl, F, R);
            }
            body_persist<<<dim3(256), 64, 0, stream>>>(
                xh, xl, bW0ih_h, bW0ih_l, bW0hh_h, bW0hh_l, bbih, bbhh,
                hA0h, hA0l, hB0h, hB0l, c0, body_last, bars);
        }

        // ---- attention + classifier (MFMA gemms, verified) ----
        split_pad<<<dim3((unsigned)((256*1024 + 255)/256)), 256, 0, stream>>>(
            body_last, bl_h, bl_l, 256, 1024, 1024);
        mfma_gemm<0><<<dim3(8*64), 64, 0, stream>>>(bl_h, bl_l, bilW_h, bilW_l,
                                                    (const float*)nullptr, u_buf, 1024, 1024, 64);
        attn_ctx<<<256, 256, 0, stream>>>(title_out, u_buf, bilb, attn_in);
        copy_rows<<<256, 256, 0, stream>>>(body_last, 1024, attn_in + 1024, 2048, 1024);
        copy_rows<<<256, 256, 0, stream>>>(title_out + 39*1024, 40*1024, out_cat, 2048, 1024);
        split_pad<<<dim3((unsigned)((256*2048 + 255)/256)), 256, 0, stream>>>(
            attn_in, ai_h, ai_l, 256, 2048, 2048);
        mfma_gemm<1><<<dim3(8*64), 64, 0, stream>>>(ai_h, ai_l, attnW_h, attnW_l,
                                                    attnb, out_cat + 1024, 2048, 2048, 64);
        split_pad<<<dim3((unsigned)((256*2048 + 255)/256)), 256, 0, stream>>>(
            out_cat, oc_h, oc_l, 256, 2048, 2048);
        mfma_gemm<0><<<dim3(8*32), 64, 0, stream>>>(oc_h, oc_l, decW_h, decW_l,
                                                    decb, ch, 512, 2048, 32);
        final_cls<<<4, 64, 0, stream>>>(ch, clsW, clsb, (float*)d_out);
    } else {
        // ================= legacy fp32 fallback =================
        float* p = (float*)d_ws;
        float* lhA0 = p; p += BATCH*HD;
        float* lc0  = p; p += BATCH*HD;
        float* lhA1 = p; p += BATCH*HD;
        float* lc1  = p; p += BATCH*HD;
        float* lhB0 = p; p += BATCH*HD;
        float* lhB1 = p; p += BATCH*HD;
        float* l_title = p; p += (size_t)BATCH*40*1024;
        float* l_blast = p; p += BATCH*1024;
        float* l_u     = p; p += BATCH*1024;
        float* l_ain   = p; p += BATCH*2048;
        float* l_ocat  = p; p += BATCH*2048;
        float* l_ch    = p; p += BATCH*512;

        hipMemsetAsync(lhA0, 0, (size_t)4*BATCH*HD*sizeof(float), stream);
        const float* tWih1 = tWih + 2048*INDIM;
        const float* tWhh1 = tWhh + 2048*HD;
        const float* bWih1 = bWih + 2048*INDIM;
        const float* bWhh1 = bWhh + 2048*HD;

        for (int t = 0; t < 40; ++t) {
            float* hi0 = (t & 1) ? lhB0 : lhA0;
            float* ho0 = (t & 1) ? lhA0 : lhB0;
            float* hi1 = (t & 1) ? lhB1 : lhA1;
            float* ho1 = (t & 1) ? lhA1 : lhB1;
            lstm_step<64><<<dim3(4,32,2), 256, 0, stream>>>(
                x, tWih, tWhh, tbih, tbhh, hi0, ho0, lc0,
                l_title + t*1024, 40*1024, t,
                tWih1, tWhh1, tbih + 2048, tbhh + 2048, hi1, ho1, lc1,
                l_title + (39 - t)*1024 + 512, 40*1024, 39 - t);
        }
        lstm_step<64><<<dim3(4,32,2), 256, 0, stream>>>(
            x, bWih, bWhh, bbih, bbhh, lhA0, lhB0, lc0, (float*)nullptr, 0, 40,
            bWih1, bWhh1, bbih + 2048, bbhh + 2048, lhA1, lhB1, lc1, l_blast + 512, 1024, 239);
        for (int t = 1; t < 200; ++t) {
            int s = 40 + t;
            float* hi = (s & 1) ? lhB0 : lhA0;
            float* ho = (s & 1) ? lhA0 : lhB0;
            float* exp_ = (t == 199) ? l_blast : (float*)nullptr;
            lstm_step<32><<<dim3(8,32,1), 256, 0, stream>>>(
                x, bWih, bWhh, bbih, bbhh, hi, ho, lc0, exp_, 1024, 40 + t,
                nullptr, nullptr, nullptr, nullptr, nullptr, nullptr, nullptr,
                (float*)nullptr, 0, 0);
        }
        gemm_bias_act<0><<<dim3(8,16), 256, 0, stream>>>(l_blast, 1024, bilW, nullptr, l_u, 1024, 1024);
        attn_ctx<<<256, 256, 0, stream>>>(l_title, l_u, bilb, l_ain);
        copy_rows<<<256, 256, 0, stream>>>(l_blast, 1024, l_ain + 1024, 2048, 1024);
        copy_rows<<<256, 256, 0, stream>>>(l_title + 39*1024, 40*1024, l_ocat, 2048, 1024);
        gemm_bias_act<1><<<dim3(8,16), 256, 0, stream>>>(l_ain, 2048, attnW, attnb, l_ocat + 1024, 2048, 2048);
        gemm_bias_act<0><<<dim3(8,8), 256, 0, stream>>>(l_ocat, 2048, decW, decb, l_ch, 512, 2048);
        final_cls<<<4, 64, 0, stream>>>(l_ch, clsW, clsb, (float*)d_out);
    }
}